// Round 3
// baseline (4036.054 us; speedup 1.0000x reference)
//
#include <hip/hip_runtime.h>
#include <hip/hip_bf16.h>

// Problem constants (fixed by reference setup_inputs)
#define NN 100000
#define NE 1600000
#define ET 1700000   // NE + NN self loops
#define NEG_SLOPE 0.2f
#define EPSI 1e-16f

// Workspace layout (float offsets). Peak requirement: 17,500,064 floats = 70 MB.
#define OFF_AS1   0            // [NN*4]
#define OFF_AD1   400000       // [NN*4]
#define OFF_XW2   800000       // [NN*32]
#define OFF_AS2   4000000      // [NN]
#define OFF_AD2   4100000      // [NN]
// ---- zero zone A start ----
#define OFF_S1    4200000      // [NN*4]
#define OFF_S2    4600000      // [NN]
#define OFF_POOL  4700000      // [64]
#define OFF_OUT1  4700064      // [NN*128]  (end = 17,500,064)
#define OFF_END   17500064
// out2 [NN*32] aliases the start of out1 (re-zeroed after k5 consumes out1)
#define OFF_OUT2  OFF_OUT1
#define ZONEA_START OFF_S1
#define ZONEA_N4    ((OFF_END - OFF_S1) / 4)          // float4 count
#define ZONEB_N4    ((NN * 32) / 4)

__device__ __forceinline__ float lrelu(float v) { return v > 0.f ? v : NEG_SLOPE * v; }

// Zero-fill (graph-capture-safe replacement for hipMemsetAsync)
__global__ void kz(float4* __restrict__ p, int n4) {
    int st = gridDim.x * 256;
    for (int i = blockIdx.x * 256 + threadIdx.x; i < n4; i += st)
        p[i] = make_float4(0.f, 0.f, 0.f, 0.f);
}

// K1: alpha_src1/alpha_dst1 (N x 4) from x @ W1 (xw1 NOT stored; recomputed in k3)
__global__ void k1_att1(const float* __restrict__ x, const float* __restrict__ W1,
                        const float* __restrict__ aw_s, const float* __restrict__ aw_d,
                        float* __restrict__ as1, float* __restrict__ ad1) {
    int t = blockIdx.x * 256 + threadIdx.x;   // t < NN*128 exactly
    int n = t >> 7, j = t & 127;
    float4 xv = *(const float4*)(x + n * 4);
    float v = xv.x * W1[j] + xv.y * W1[128 + j] + xv.z * W1[256 + j] + xv.w * W1[384 + j];
    float ps = v * aw_s[j];
    float pd = v * aw_d[j];
#pragma unroll
    for (int m = 1; m < 32; m <<= 1) { ps += __shfl_xor(ps, m); pd += __shfl_xor(pd, m); }
    if ((j & 31) == 0) { int h = j >> 5; as1[n * 4 + h] = ps; ad1[n * 4 + h] = pd; }
}

// K2: conv1 softmax denominators: s1[dst][h] += exp(leaky(as1[src][h]+ad1[dst][h]))
__global__ void k2_den1(const int* __restrict__ ei, const float* __restrict__ as1,
                        const float* __restrict__ ad1, float* __restrict__ s1) {
    int e = blockIdx.x * 256 + threadIdx.x;
    if (e >= ET) return;
    int s_, d_;
    if (e < NE) { s_ = ei[e]; d_ = ei[NE + e]; } else { s_ = d_ = e - NE; }
    float4 a = *(const float4*)(as1 + s_ * 4);
    float4 b = *(const float4*)(ad1 + d_ * 4);
    float* sd = s1 + d_ * 4;
    unsafeAtomicAdd(sd + 0, __expf(lrelu(a.x + b.x)));
    unsafeAtomicAdd(sd + 1, __expf(lrelu(a.y + b.y)));
    unsafeAtomicAdd(sd + 2, __expf(lrelu(a.z + b.z)));
    unsafeAtomicAdd(sd + 3, __expf(lrelu(a.w + b.w)));
}

// K3: conv1 scatter: out1[dst] += (x[src]@W1) * alpha  (32 lanes per edge, float4 each)
__global__ void k3_msg1(const int* __restrict__ ei, const float* __restrict__ x,
                        const float* __restrict__ W1, const float* __restrict__ as1,
                        const float* __restrict__ ad1, const float* __restrict__ s1,
                        float* __restrict__ out1) {
    int t = blockIdx.x * 256 + threadIdx.x;   // ET*32 threads exactly
    int e = t >> 5, l = t & 31;
    int s_, d_;
    if (e < NE) { s_ = ei[e]; d_ = ei[NE + e]; } else { s_ = d_ = e - NE; }
    int h = l >> 3;                           // head for these 4 features
    float eh = as1[s_ * 4 + h] + ad1[d_ * 4 + h];
    float alpha = __expf(lrelu(eh)) / (s1[d_ * 4 + h] + EPSI);
    float4 xv = *(const float4*)(x + s_ * 4);             // broadcast within wave
    float4 w0 = *(const float4*)(W1 + 0 * 128 + l * 4);   // L1-resident (2 KB)
    float4 w1 = *(const float4*)(W1 + 1 * 128 + l * 4);
    float4 w2 = *(const float4*)(W1 + 2 * 128 + l * 4);
    float4 w3 = *(const float4*)(W1 + 3 * 128 + l * 4);
    float* o = out1 + d_ * 128 + l * 4;
    unsafeAtomicAdd(o + 0, (xv.x * w0.x + xv.y * w1.x + xv.z * w2.x + xv.w * w3.x) * alpha);
    unsafeAtomicAdd(o + 1, (xv.x * w0.y + xv.y * w1.y + xv.z * w2.y + xv.w * w3.y) * alpha);
    unsafeAtomicAdd(o + 2, (xv.x * w0.z + xv.y * w1.z + xv.z * w2.z + xv.w * w3.z) * alpha);
    unsafeAtomicAdd(o + 3, (xv.x * w0.w + xv.y * w1.w + xv.z * w2.w + xv.w * w3.w) * alpha);
}

// K5: h = elu(out1 + b1); xw2 = h @ W2 (N x 32); alpha_src2/alpha_dst2 (N)
__global__ void k5_xw2(const float* __restrict__ out1, const float* __restrict__ b1,
                       const float* __restrict__ W2, const float* __restrict__ aw_s2,
                       const float* __restrict__ aw_d2, float* __restrict__ xw2,
                       float* __restrict__ as2, float* __restrict__ ad2) {
    __shared__ float hs[8 * 128];
    int n0 = blockIdx.x * 8;
    int tid = threadIdx.x;
    for (int i = tid; i < 1024; i += 256) {
        int k = i & 127;
        float v = out1[n0 * 128 + i] + b1[k];
        hs[i] = v > 0.f ? v : (__expf(v) - 1.f);
    }
    __syncthreads();
    int ln = tid >> 5, f = tid & 31;
    int n = n0 + ln;
    const float* hr = hs + ln * 128;
    float acc = 0.f;
#pragma unroll 8
    for (int k = 0; k < 128; k++) acc += hr[k] * W2[k * 32 + f];
    xw2[n * 32 + f] = acc;
    float ps = acc * aw_s2[f];
    float pd = acc * aw_d2[f];
#pragma unroll
    for (int m = 1; m < 32; m <<= 1) { ps += __shfl_xor(ps, m); pd += __shfl_xor(pd, m); }
    if (f == 0) { as2[n] = ps; ad2[n] = pd; }
}

// K6: conv2 softmax denominators
__global__ void k6_den2(const int* __restrict__ ei, const float* __restrict__ as2,
                        const float* __restrict__ ad2, float* __restrict__ s2) {
    int e = blockIdx.x * 256 + threadIdx.x;
    if (e >= ET) return;
    int s_, d_;
    if (e < NE) { s_ = ei[e]; d_ = ei[NE + e]; } else { s_ = d_ = e - NE; }
    unsafeAtomicAdd(s2 + d_, __expf(lrelu(as2[s_] + ad2[d_])));
}

// K7: conv2 scatter + attn output (8 lanes per edge, float4 each)
__global__ void k7_msg2(const int* __restrict__ ei, const float* __restrict__ as2,
                        const float* __restrict__ ad2, const float* __restrict__ s2,
                        const float* __restrict__ xw2, float* __restrict__ out2,
                        float* __restrict__ attn) {
    int t = blockIdx.x * 256 + threadIdx.x;   // ET*8 threads exactly
    int e = t >> 3, l = t & 7;
    int s_, d_;
    if (e < NE) { s_ = ei[e]; d_ = ei[NE + e]; } else { s_ = d_ = e - NE; }
    float alpha = __expf(lrelu(as2[s_] + ad2[d_])) / (s2[d_] + EPSI);
    float4 xv = *(const float4*)(xw2 + s_ * 32 + l * 4);
    float* o = out2 + d_ * 32 + l * 4;
    unsafeAtomicAdd(o + 0, xv.x * alpha);
    unsafeAtomicAdd(o + 1, xv.y * alpha);
    unsafeAtomicAdd(o + 2, xv.z * alpha);
    unsafeAtomicAdd(o + 3, xv.w * alpha);
    if (l == 0) attn[e] = alpha;
}

// K8: pooled sums: pool[f] += sum_n elu(out2[n][f] + b2[f])
__global__ void k8_pool(const float* __restrict__ out2, const float* __restrict__ b2,
                        float* __restrict__ pool) {
    int tid = threadIdx.x;
    int f = tid & 31;
    float bb = b2[f];
    float acc = 0.f;
    int st = gridDim.x * 256;
    for (int i = blockIdx.x * 256 + tid; i < NN * 32; i += st) {
        float v = out2[i] + bb;
        acc += v > 0.f ? v : (__expf(v) - 1.f);
    }
    acc += __shfl_xor(acc, 32);
    if ((tid & 63) < 32) unsafeAtomicAdd(&pool[f], acc);
}

// K9: logits = (pool/N) @ lin_w + lin_b
__global__ void k9_logits(const float* __restrict__ pool, const float* __restrict__ lin_w,
                          const float* __restrict__ lin_b, float* __restrict__ out) {
    int j = threadIdx.x;
    if (j < 2) {
        float s = 0.f;
        for (int f = 0; f < 32; f++) s += (pool[f] * (1.0f / NN)) * lin_w[f * 2 + j];
        out[j] = s + lin_b[j];
    }
}

extern "C" void kernel_launch(void* const* d_in, const int* in_sizes, int n_in,
                              void* d_out, int out_size, void* d_ws, size_t ws_size,
                              hipStream_t stream) {
    const float* x    = (const float*)d_in[0];
    const int*   ei   = (const int*)d_in[1];    // harness converts int64 -> int32
    const float* W1   = (const float*)d_in[2];
    const float* aS1  = (const float*)d_in[3];
    const float* aD1  = (const float*)d_in[4];
    const float* b1   = (const float*)d_in[5];
    const float* W2   = (const float*)d_in[6];
    const float* aS2  = (const float*)d_in[7];
    const float* aD2  = (const float*)d_in[8];
    const float* b2   = (const float*)d_in[9];
    const float* linw = (const float*)d_in[10];
    const float* linb = (const float*)d_in[11];

    float* ws   = (float*)d_ws;
    float* as1  = ws + OFF_AS1;
    float* ad1  = ws + OFF_AD1;
    float* xw2  = ws + OFF_XW2;
    float* as2  = ws + OFF_AS2;
    float* ad2  = ws + OFF_AD2;
    float* s1   = ws + OFF_S1;
    float* s2   = ws + OFF_S2;
    float* pool = ws + OFF_POOL;
    float* out1 = ws + OFF_OUT1;
    float* out2 = ws + OFF_OUT2;   // aliases out1 (re-zeroed after k5)

    float* logits = (float*)d_out;
    float* attn   = (float*)d_out + 2;

    // zero accumulators (kernel, not memset: graph-capture-safe)
    kz<<<2048, 256, 0, stream>>>((float4*)(ws + ZONEA_START), ZONEA_N4);

    k1_att1<<<(NN * 128) / 256, 256, 0, stream>>>(x, W1, aS1, aD1, as1, ad1);
    k2_den1<<<(ET + 255) / 256, 256, 0, stream>>>(ei, as1, ad1, s1);
    k3_msg1<<<(ET * 32) / 256, 256, 0, stream>>>(ei, x, W1, as1, ad1, s1, out1);
    k5_xw2<<<NN / 8, 256, 0, stream>>>(out1, b1, W2, aS2, aD2, xw2, as2, ad2);
    // out1 fully consumed; re-zero its head for out2 accumulation
    kz<<<1024, 256, 0, stream>>>((float4*)(ws + OFF_OUT2), ZONEB_N4);
    k6_den2<<<(ET + 255) / 256, 256, 0, stream>>>(ei, as2, ad2, s2);
    k7_msg2<<<(ET * 8) / 256, 256, 0, stream>>>(ei, as2, ad2, s2, xw2, out2, attn);
    k8_pool<<<1024, 256, 0, stream>>>(out2, b2, pool);
    k9_logits<<<1, 64, 0, stream>>>(pool, linw, linb, logits);
}

// Round 4
// 895.830 us; speedup vs baseline: 4.5054x; 4.5054x over previous
//
#include <hip/hip_runtime.h>
#include <hip/hip_bf16.h>

// Problem constants (fixed by reference setup_inputs)
#define NN 100000
#define NE 1600000
#define ET 1700000   // NE + NN self loops
#define NEG_SLOPE 0.2f
#define EPSI 1e-16f

// Workspace layout (4-byte element offsets). Total 11,100,100 elems = 44.4 MB.
#define OFF_WF     0         // [32]   folded W1@att vectors
#define OFF_AS1    32        // [NN*4]
#define OFF_AD1    400032    // [NN*4]
#define OFF_XW2    800032    // [NN*32]
#define OFF_AS2    4000032   // [NN]
#define OFF_AD2    4100032   // [NN]
#define OFF_OFFS   4200032   // [NN+1] int
#define OFF_CUR    4300034   // [NN] int
#define OFF_EDATA  4400034   // [ET] int2 (byte off 17600136, 8B-aligned)
#define OFF_DEG    7800036   // [NN] int   (16B-aligned: zero-zone start)
#define OFF_POOL   7900036   // [64]
#define OFF_OUT2   7900100   // [NN*32]  (16B-aligned)
#define ZERO_START OFF_DEG
#define ZERO_N4    ((7900100 - OFF_DEG) / 4)   // 25016 float4 (deg + pool)

__device__ __forceinline__ float lrelu(float v) { return v > 0.f ? v : NEG_SLOPE * v; }

// Zero-fill (graph-capture-safe)
__global__ void kz(float4* __restrict__ p, int n4) {
    int st = gridDim.x * 256;
    for (int i = blockIdx.x * 256 + threadIdx.x; i < n4; i += st)
        p[i] = make_float4(0.f, 0.f, 0.f, 0.f);
}

// K0: fold W1 with att vectors: wf[k*4+h] = sum_f W1[k,h*32+f]*aS1[h,f]; +16 for aD1
__global__ void k0_wfold(const float* __restrict__ W1, const float* __restrict__ aS1,
                         const float* __restrict__ aD1, float* __restrict__ wf) {
    int t = threadIdx.x;
    if (t < 32) {
        int u = t & 15, k = u >> 2, h = u & 3;
        const float* av = (t < 16) ? aS1 : aD1;
        float s = 0.f;
        for (int f = 0; f < 32; f++) s += W1[k * 128 + h * 32 + f] * av[h * 32 + f];
        wf[t] = s;
    }
}

// K1: as1[n,h] = x[n,:]@wf[:,h]; ad1 likewise (one thread per node)
__global__ void k1_att1(const float* __restrict__ x, const float* __restrict__ wf,
                        float* __restrict__ as1, float* __restrict__ ad1) {
    int n = blockIdx.x * 256 + threadIdx.x;
    if (n >= NN) return;
    float4 xv = *(const float4*)(x + n * 4);
#pragma unroll
    for (int h = 0; h < 4; h++) {
        as1[n * 4 + h] = xv.x * wf[h] + xv.y * wf[4 + h] + xv.z * wf[8 + h] + xv.w * wf[12 + h];
        ad1[n * 4 + h] = xv.x * wf[16 + h] + xv.y * wf[20 + h] + xv.z * wf[24 + h] + xv.w * wf[28 + h];
    }
}

// CSR build: degree histogram
__global__ void kc1_deg(const int* __restrict__ ei, int* __restrict__ deg) {
    int e = blockIdx.x * 256 + threadIdx.x;
    if (e >= ET) return;
    int d_ = (e < NE) ? ei[NE + e] : (e - NE);
    atomicAdd(&deg[d_], 1);
}

// CSR build: single-workgroup exclusive scan (1024 threads, 98 elems each)
__global__ void kc2_scan(const int* __restrict__ deg, int* __restrict__ offs,
                         int* __restrict__ cursor) {
    __shared__ int psum[1024];
    int tid = threadIdx.x;
    const int CH = (NN + 1023) / 1024;   // 98
    int base = tid * CH;
    int s = 0;
    for (int i = 0; i < CH; i++) { int idx = base + i; if (idx < NN) s += deg[idx]; }
    psum[tid] = s;
    __syncthreads();
    for (int off = 1; off < 1024; off <<= 1) {
        int v = (tid >= off) ? psum[tid - off] : 0;
        __syncthreads();
        psum[tid] += v;
        __syncthreads();
    }
    int run = (tid == 0) ? 0 : psum[tid - 1];
    for (int i = 0; i < CH; i++) {
        int idx = base + i;
        if (idx < NN) { offs[idx] = run; cursor[idx] = run; run += deg[idx]; }
    }
    if (tid == 1023) offs[NN] = run;   // == ET
}

// CSR build: fill (src, edge-id) per dst bucket
__global__ void kc3_fill(const int* __restrict__ ei, int* __restrict__ cursor,
                         int2* __restrict__ edata) {
    int e = blockIdx.x * 256 + threadIdx.x;
    if (e >= ET) return;
    int s_, d_;
    if (e < NE) { s_ = ei[e]; d_ = ei[NE + e]; } else { s_ = d_ = e - NE; }
    int pos = atomicAdd(&cursor[d_], 1);
    edata[pos] = make_int2(s_, e);
}

// K4: fused conv1 gather (no atomics) + elu + @W2 + att2 projections.
// One wave (64 lanes) per node; lane owns features f0=2*ln, f0+1 of the 128.
__global__ __launch_bounds__(256) void k4_conv1(
    const int* __restrict__ offs, const int2* __restrict__ edata,
    const float* __restrict__ x, const float* __restrict__ W1,
    const float* __restrict__ b1, const float* __restrict__ W2,
    const float* __restrict__ as1, const float* __restrict__ ad1,
    const float* __restrict__ aw_s2, const float* __restrict__ aw_d2,
    float* __restrict__ xw2, float* __restrict__ as2, float* __restrict__ ad2) {
    __shared__ float hs[4][128];
    int wv = threadIdx.x >> 6, ln = threadIdx.x & 63;
    int n = blockIdx.x * 4 + wv;            // grid exact: 25000*4 = NN
    int f0 = ln * 2;
    int h = f0 >> 5;
    float w00 = W1[f0],       w01 = W1[f0 + 1];
    float w10 = W1[128 + f0], w11 = W1[128 + f0 + 1];
    float w20 = W1[256 + f0], w21 = W1[256 + f0 + 1];
    float w30 = W1[384 + f0], w31 = W1[384 + f0 + 1];
    float ad = ad1[n * 4 + h];
    float acc0 = 0.f, acc1 = 0.f, den = 0.f;
    int beg = offs[n], end = offs[n + 1];
    for (int j = beg; j < end; j++) {
        int2 ed = edata[j];
        float ex = __expf(lrelu(as1[ed.x * 4 + h] + ad));
        den += ex;
        float4 xv = *(const float4*)(x + ed.x * 4);
        acc0 += ex * (xv.x * w00 + xv.y * w10 + xv.z * w20 + xv.w * w30);
        acc1 += ex * (xv.x * w01 + xv.y * w11 + xv.z * w21 + xv.w * w31);
    }
    float inv = 1.f / (den + EPSI);
    float h0 = acc0 * inv + b1[f0], h1 = acc1 * inv + b1[f0 + 1];
    h0 = h0 > 0.f ? h0 : (__expf(h0) - 1.f);
    h1 = h1 > 0.f ? h1 : (__expf(h1) - 1.f);
    hs[wv][f0] = h0; hs[wv][f0 + 1] = h1;
    __syncthreads();
    // xw2[n,f] = sum_k h[k]*W2[k,f]; lanes f and f+32 split k-halves
    int f = ln & 31, kb = (ln >> 5) * 64;
    float a = 0.f;
#pragma unroll
    for (int k = 0; k < 64; k++) a += hs[wv][kb + k] * W2[(kb + k) * 32 + f];
    a += __shfl_xor(a, 32);
    float ps = a * aw_s2[f], pd = a * aw_d2[f];
#pragma unroll
    for (int m = 1; m < 32; m <<= 1) { ps += __shfl_xor(ps, m); pd += __shfl_xor(pd, m); }
    if (ln < 32) xw2[n * 32 + f] = a;
    if (ln == 0) { as2[n] = ps; ad2[n] = pd; }
}

// K6: conv2 gather (no atomics) + attn write. 32 lanes per node, 8 nodes/block.
__global__ __launch_bounds__(256) void k6_conv2(
    const int* __restrict__ offs, const int2* __restrict__ edata,
    const float* __restrict__ xw2, const float* __restrict__ as2,
    const float* __restrict__ ad2, float* __restrict__ out2,
    float* __restrict__ attn) {
    int sub = threadIdx.x >> 5, f = threadIdx.x & 31;
    int n = blockIdx.x * 8 + sub;           // grid exact: 12500*8 = NN
    float ad = ad2[n];
    float den = 0.f, acc = 0.f;
    int beg = offs[n], end = offs[n + 1];
    for (int j = beg; j < end; j++) {
        int2 ed = edata[j];
        float ex = __expf(lrelu(as2[ed.x] + ad));
        den += ex;
        acc += ex * xw2[ed.x * 32 + f];
    }
    float inv = 1.f / (den + EPSI);
    out2[n * 32 + f] = acc * inv;
    for (int j = beg + f; j < end; j += 32) {
        int2 ed = edata[j];
        float ex = __expf(lrelu(as2[ed.x] + ad));
        attn[ed.y] = ex * inv;
    }
}

// K8: pooled sums: pool[f] += sum_n elu(out2[n][f] + b2[f])
__global__ void k8_pool(const float* __restrict__ out2, const float* __restrict__ b2,
                        float* __restrict__ pool) {
    int tid = threadIdx.x;
    int f = tid & 31;
    float bb = b2[f];
    float acc = 0.f;
    int st = gridDim.x * 256;
    for (int i = blockIdx.x * 256 + tid; i < NN * 32; i += st) {
        float v = out2[i] + bb;
        acc += v > 0.f ? v : (__expf(v) - 1.f);
    }
    acc += __shfl_xor(acc, 32);
    if ((tid & 63) < 32) unsafeAtomicAdd(&pool[f], acc);
}

// K9: logits = (pool/N) @ lin_w + lin_b
__global__ void k9_logits(const float* __restrict__ pool, const float* __restrict__ lin_w,
                          const float* __restrict__ lin_b, float* __restrict__ out) {
    int j = threadIdx.x;
    if (j < 2) {
        float s = 0.f;
        for (int f = 0; f < 32; f++) s += (pool[f] * (1.0f / NN)) * lin_w[f * 2 + j];
        out[j] = s + lin_b[j];
    }
}

extern "C" void kernel_launch(void* const* d_in, const int* in_sizes, int n_in,
                              void* d_out, int out_size, void* d_ws, size_t ws_size,
                              hipStream_t stream) {
    const float* x    = (const float*)d_in[0];
    const int*   ei   = (const int*)d_in[1];    // harness converts int64 -> int32
    const float* W1   = (const float*)d_in[2];
    const float* aS1  = (const float*)d_in[3];
    const float* aD1  = (const float*)d_in[4];
    const float* b1   = (const float*)d_in[5];
    const float* W2   = (const float*)d_in[6];
    const float* aS2  = (const float*)d_in[7];
    const float* aD2  = (const float*)d_in[8];
    const float* b2   = (const float*)d_in[9];
    const float* linw = (const float*)d_in[10];
    const float* linb = (const float*)d_in[11];

    float* ws   = (float*)d_ws;
    float* wf   = ws + OFF_WF;
    float* as1  = ws + OFF_AS1;
    float* ad1  = ws + OFF_AD1;
    float* xw2  = ws + OFF_XW2;
    float* as2  = ws + OFF_AS2;
    float* ad2  = ws + OFF_AD2;
    int*   offs = (int*)(ws + OFF_OFFS);
    int*   cur  = (int*)(ws + OFF_CUR);
    int2*  ed   = (int2*)(ws + OFF_EDATA);
    int*   deg  = (int*)(ws + OFF_DEG);
    float* pool = ws + OFF_POOL;
    float* out2 = ws + OFF_OUT2;

    float* logits = (float*)d_out;
    float* attn   = (float*)d_out + 2;

    kz<<<98, 256, 0, stream>>>((float4*)(ws + ZERO_START), ZERO_N4);   // deg + pool
    k0_wfold<<<1, 64, 0, stream>>>(W1, aS1, aD1, wf);
    k1_att1<<<(NN + 255) / 256, 256, 0, stream>>>(x, wf, as1, ad1);
    kc1_deg<<<(ET + 255) / 256, 256, 0, stream>>>(ei, deg);
    kc2_scan<<<1, 1024, 0, stream>>>(deg, offs, cur);
    kc3_fill<<<(ET + 255) / 256, 256, 0, stream>>>(ei, cur, ed);
    k4_conv1<<<NN / 4, 256, 0, stream>>>(offs, ed, x, W1, b1, W2, as1, ad1,
                                         aS2, aD2, xw2, as2, ad2);
    k6_conv2<<<NN / 8, 256, 0, stream>>>(offs, ed, xw2, as2, ad2, out2, attn);
    k8_pool<<<1024, 256, 0, stream>>>(out2, b2, pool);
    k9_logits<<<1, 64, 0, stream>>>(pool, linw, linb, logits);
}

// Round 5
// 622.519 us; speedup vs baseline: 6.4834x; 1.4390x over previous
//
#include <hip/hip_runtime.h>
#include <hip/hip_bf16.h>

// Problem constants (fixed by reference setup_inputs)
#define NN 100000
#define NE 1600000
#define ET 1700000   // NE + NN self loops
#define NEG_SLOPE 0.2f
#define EPSI 1e-16f

#define SCAN_NB 98            // 98 blocks * 1024 elems >= NN
#define DEG_PAD (SCAN_NB * 1024)   // 100352

// Workspace layout (4-byte element offsets). Total ~11.1M elems = 44.4 MB.
#define OFF_WF     0         // [32]
#define OFF_AS1    32        // [NN*4]
#define OFF_AD1    400032    // [NN*4]
#define OFF_XW2    800032    // [NN*32]
#define OFF_AS2    4000032   // [NN]
#define OFF_AD2    4100032   // [NN]
#define OFF_OFFS   4200032   // [NN+1] int
#define OFF_CUR    4300034   // [NN] int
#define OFF_EDATA  4400034   // [ET] int2 (byte 17600136, 8B aligned)
#define OFF_DEG    7800036   // [DEG_PAD] int (byte 31200144, 16B aligned) -- zero zone
#define OFF_POOL   7900388   // [64]
#define OFF_BSUM   7900452   // [98] int
#define OFF_BPRE   7900550   // [100] int
#define OFF_OUT2   7900656   // [NN*32] (byte 31602624, 16B aligned)
#define ZERO_START OFF_DEG
#define ZERO_N4    ((DEG_PAD + 64) / 4)    // deg + pool = 25104 float4

__device__ __forceinline__ float lrelu(float v) { return v > 0.f ? v : NEG_SLOPE * v; }

// Zero-fill (graph-capture-safe)
__global__ void kz(float4* __restrict__ p, int n4) {
    int st = gridDim.x * 256;
    for (int i = blockIdx.x * 256 + threadIdx.x; i < n4; i += st)
        p[i] = make_float4(0.f, 0.f, 0.f, 0.f);
}

// K0: fold W1 with att vectors: wf[k*4+h] = sum_f W1[k,h*32+f]*a[h,f]
__global__ void k0_wfold(const float* __restrict__ W1, const float* __restrict__ aS1,
                         const float* __restrict__ aD1, float* __restrict__ wf) {
    int t = threadIdx.x;
    if (t < 32) {
        int u = t & 15, k = u >> 2, h = u & 3;
        const float* av = (t < 16) ? aS1 : aD1;
        float s = 0.f;
        for (int f = 0; f < 32; f++) s += W1[k * 128 + h * 32 + f] * av[h * 32 + f];
        wf[t] = s;
    }
}

// K1: as1[n,h] = x[n,:]@wf[:,h]; ad1 likewise
__global__ void k1_att1(const float* __restrict__ x, const float* __restrict__ wf,
                        float* __restrict__ as1, float* __restrict__ ad1) {
    int n = blockIdx.x * 256 + threadIdx.x;
    if (n >= NN) return;
    float4 xv = *(const float4*)(x + n * 4);
#pragma unroll
    for (int h = 0; h < 4; h++) {
        as1[n * 4 + h] = xv.x * wf[h] + xv.y * wf[4 + h] + xv.z * wf[8 + h] + xv.w * wf[12 + h];
        ad1[n * 4 + h] = xv.x * wf[16 + h] + xv.y * wf[20 + h] + xv.z * wf[24 + h] + xv.w * wf[28 + h];
    }
}

// CSR: degree histogram
__global__ void kc1_deg(const int* __restrict__ ei, int* __restrict__ deg) {
    int e = blockIdx.x * 256 + threadIdx.x;
    if (e >= ET) return;
    int d_ = (e < NE) ? ei[NE + e] : (e - NE);
    atomicAdd(&deg[d_], 1);
}

// Two-level scan, phase A: per-block (1024 elems) sums
__global__ void kc2a(const int* __restrict__ deg, int* __restrict__ bsum) {
    __shared__ int ws_[4];
    int b = blockIdx.x, t = threadIdx.x;
    int4 d = *(const int4*)(deg + b * 1024 + t * 4);   // deg padded+zeroed: safe
    int s = d.x + d.y + d.z + d.w;
#pragma unroll
    for (int m = 1; m < 64; m <<= 1) s += __shfl_xor(s, m);
    if ((t & 63) == 0) ws_[t >> 6] = s;
    __syncthreads();
    if (t == 0) bsum[b] = ws_[0] + ws_[1] + ws_[2] + ws_[3];
}

// Phase B: scan 98 block sums (1 block), write offs[NN]=total
__global__ void kc2b(const int* __restrict__ bsum, int* __restrict__ bpre,
                     int* __restrict__ offs) {
    __shared__ int ts[128];
    int t = threadIdx.x;
    int v = (t < SCAN_NB) ? bsum[t] : 0;
    ts[t] = v;
    __syncthreads();
    for (int off = 1; off < 128; off <<= 1) {
        int u = (t >= off) ? ts[t - off] : 0;
        __syncthreads();
        ts[t] += u;
        __syncthreads();
    }
    if (t < SCAN_NB) bpre[t] = (t == 0) ? 0 : ts[t - 1];
    if (t == SCAN_NB - 1) offs[NN] = ts[t];   // == ET
}

// Phase C: intra-block exclusive scan + block prefix -> offs, cursor
__global__ void kc2c(const int* __restrict__ deg, const int* __restrict__ bpre,
                     int* __restrict__ offs, int* __restrict__ cur) {
    __shared__ int ts[256];
    int b = blockIdx.x, t = threadIdx.x;
    int base = b * 1024 + t * 4;
    int4 d = *(const int4*)(deg + base);
    int s = d.x + d.y + d.z + d.w;
    ts[t] = s;
    __syncthreads();
    for (int off = 1; off < 256; off <<= 1) {
        int u = (t >= off) ? ts[t - off] : 0;
        __syncthreads();
        ts[t] += u;
        __syncthreads();
    }
    int r = bpre[b] + ((t == 0) ? 0 : ts[t - 1]);
    if (base < NN)     { offs[base] = r;     cur[base] = r; }     r += d.x;
    if (base + 1 < NN) { offs[base + 1] = r; cur[base + 1] = r; } r += d.y;
    if (base + 2 < NN) { offs[base + 2] = r; cur[base + 2] = r; } r += d.z;
    if (base + 3 < NN) { offs[base + 3] = r; cur[base + 3] = r; }
}

// CSR: fill (src, edge-id) per dst bucket
__global__ void kc3_fill(const int* __restrict__ ei, int* __restrict__ cursor,
                         int2* __restrict__ edata) {
    int e = blockIdx.x * 256 + threadIdx.x;
    if (e >= ET) return;
    int s_, d_;
    if (e < NE) { s_ = ei[e]; d_ = ei[NE + e]; } else { s_ = d_ = e - NE; }
    int pos = atomicAdd(&cursor[d_], 1);
    edata[pos] = make_int2(s_, e);
}

// K4: fused conv1 gather + elu + @W2 + att2 projections. One wave per node.
__global__ __launch_bounds__(256) void k4_conv1(
    const int* __restrict__ offs, const int2* __restrict__ edata,
    const float* __restrict__ x, const float* __restrict__ W1,
    const float* __restrict__ b1, const float* __restrict__ W2,
    const float* __restrict__ as1, const float* __restrict__ ad1,
    const float* __restrict__ aw_s2, const float* __restrict__ aw_d2,
    float* __restrict__ xw2, float* __restrict__ as2, float* __restrict__ ad2) {
    __shared__ float hs[4][128];
    int wv = threadIdx.x >> 6, ln = threadIdx.x & 63;
    int n = blockIdx.x * 4 + wv;            // grid exact: 25000*4 = NN
    int f0 = ln * 2;
    int h = f0 >> 5;
    float w00 = W1[f0],       w01 = W1[f0 + 1];
    float w10 = W1[128 + f0], w11 = W1[128 + f0 + 1];
    float w20 = W1[256 + f0], w21 = W1[256 + f0 + 1];
    float w30 = W1[384 + f0], w31 = W1[384 + f0 + 1];
    float ad = ad1[n * 4 + h];
    float acc0 = 0.f, acc1 = 0.f, den = 0.f;
    int beg = offs[n], end = offs[n + 1];
    for (int j = beg; j < end; j++) {
        int2 ed = edata[j];
        float ex = __expf(lrelu(as1[ed.x * 4 + h] + ad));
        den += ex;
        float4 xv = *(const float4*)(x + ed.x * 4);
        acc0 += ex * (xv.x * w00 + xv.y * w10 + xv.z * w20 + xv.w * w30);
        acc1 += ex * (xv.x * w01 + xv.y * w11 + xv.z * w21 + xv.w * w31);
    }
    float inv = 1.f / (den + EPSI);
    float h0 = acc0 * inv + b1[f0], h1 = acc1 * inv + b1[f0 + 1];
    h0 = h0 > 0.f ? h0 : (__expf(h0) - 1.f);
    h1 = h1 > 0.f ? h1 : (__expf(h1) - 1.f);
    hs[wv][f0] = h0; hs[wv][f0 + 1] = h1;
    __syncthreads();
    int f = ln & 31, kb = (ln >> 5) * 64;
    float a = 0.f;
#pragma unroll
    for (int k = 0; k < 64; k++) a += hs[wv][kb + k] * W2[(kb + k) * 32 + f];
    a += __shfl_xor(a, 32);
    float ps = a * aw_s2[f], pd = a * aw_d2[f];
#pragma unroll
    for (int m = 1; m < 32; m <<= 1) { ps += __shfl_xor(ps, m); pd += __shfl_xor(pd, m); }
    if (ln < 32) xw2[n * 32 + f] = a;
    if (ln == 0) { as2[n] = ps; ad2[n] = pd; }
}

// K6: conv2 gather + attn write. 32 lanes per node, 8 nodes/block.
__global__ __launch_bounds__(256) void k6_conv2(
    const int* __restrict__ offs, const int2* __restrict__ edata,
    const float* __restrict__ xw2, const float* __restrict__ as2,
    const float* __restrict__ ad2, float* __restrict__ out2,
    float* __restrict__ attn) {
    int sub = threadIdx.x >> 5, f = threadIdx.x & 31;
    int n = blockIdx.x * 8 + sub;           // grid exact: 12500*8 = NN
    float ad = ad2[n];
    float den = 0.f, acc = 0.f;
    int beg = offs[n], end = offs[n + 1];
    for (int j = beg; j < end; j++) {
        int2 ed = edata[j];
        float ex = __expf(lrelu(as2[ed.x] + ad));
        den += ex;
        acc += ex * xw2[ed.x * 32 + f];
    }
    float inv = 1.f / (den + EPSI);
    out2[n * 32 + f] = acc * inv;
    for (int j = beg + f; j < end; j += 32) {
        int2 ed = edata[j];
        float ex = __expf(lrelu(as2[ed.x] + ad));
        attn[ed.y] = ex * inv;
    }
}

// K8: pooled sums
__global__ void k8_pool(const float* __restrict__ out2, const float* __restrict__ b2,
                        float* __restrict__ pool) {
    int tid = threadIdx.x;
    int f = tid & 31;
    float bb = b2[f];
    float acc = 0.f;
    int st = gridDim.x * 256;
    for (int i = blockIdx.x * 256 + tid; i < NN * 32; i += st) {
        float v = out2[i] + bb;
        acc += v > 0.f ? v : (__expf(v) - 1.f);
    }
    acc += __shfl_xor(acc, 32);
    if ((tid & 63) < 32) unsafeAtomicAdd(&pool[f], acc);
}

// K9: logits
__global__ void k9_logits(const float* __restrict__ pool, const float* __restrict__ lin_w,
                          const float* __restrict__ lin_b, float* __restrict__ out) {
    int j = threadIdx.x;
    if (j < 2) {
        float s = 0.f;
        for (int f = 0; f < 32; f++) s += (pool[f] * (1.0f / NN)) * lin_w[f * 2 + j];
        out[j] = s + lin_b[j];
    }
}

extern "C" void kernel_launch(void* const* d_in, const int* in_sizes, int n_in,
                              void* d_out, int out_size, void* d_ws, size_t ws_size,
                              hipStream_t stream) {
    const float* x    = (const float*)d_in[0];
    const int*   ei   = (const int*)d_in[1];    // harness converts int64 -> int32
    const float* W1   = (const float*)d_in[2];
    const float* aS1  = (const float*)d_in[3];
    const float* aD1  = (const float*)d_in[4];
    const float* b1   = (const float*)d_in[5];
    const float* W2   = (const float*)d_in[6];
    const float* aS2  = (const float*)d_in[7];
    const float* aD2  = (const float*)d_in[8];
    const float* b2   = (const float*)d_in[9];
    const float* linw = (const float*)d_in[10];
    const float* linb = (const float*)d_in[11];

    float* ws   = (float*)d_ws;
    float* wf   = ws + OFF_WF;
    float* as1  = ws + OFF_AS1;
    float* ad1  = ws + OFF_AD1;
    float* xw2  = ws + OFF_XW2;
    float* as2  = ws + OFF_AS2;
    float* ad2  = ws + OFF_AD2;
    int*   offs = (int*)(ws + OFF_OFFS);
    int*   cur  = (int*)(ws + OFF_CUR);
    int2*  ed   = (int2*)(ws + OFF_EDATA);
    int*   deg  = (int*)(ws + OFF_DEG);
    float* pool = ws + OFF_POOL;
    int*   bsum = (int*)(ws + OFF_BSUM);
    int*   bpre = (int*)(ws + OFF_BPRE);
    float* out2 = ws + OFF_OUT2;

    float* logits = (float*)d_out;
    float* attn   = (float*)d_out + 2;

    kz<<<98, 256, 0, stream>>>((float4*)(ws + ZERO_START), ZERO_N4);   // deg + pool
    k0_wfold<<<1, 64, 0, stream>>>(W1, aS1, aD1, wf);
    k1_att1<<<(NN + 255) / 256, 256, 0, stream>>>(x, wf, as1, ad1);
    kc1_deg<<<(ET + 255) / 256, 256, 0, stream>>>(ei, deg);
    kc2a<<<SCAN_NB, 256, 0, stream>>>(deg, bsum);
    kc2b<<<1, 128, 0, stream>>>(bsum, bpre, offs);
    kc2c<<<SCAN_NB, 256, 0, stream>>>(deg, bpre, offs, cur);
    kc3_fill<<<(ET + 255) / 256, 256, 0, stream>>>(ei, cur, ed);
    k4_conv1<<<NN / 4, 256, 0, stream>>>(offs, ed, x, W1, b1, W2, as1, ad1,
                                         aS2, aD2, xw2, as2, ad2);
    k6_conv2<<<NN / 8, 256, 0, stream>>>(offs, ed, xw2, as2, ad2, out2, attn);
    k8_pool<<<1024, 256, 0, stream>>>(out2, b2, pool);
    k9_logits<<<1, 64, 0, stream>>>(pool, linw, linb, logits);
}

// Round 6
// 462.939 us; speedup vs baseline: 8.7183x; 1.3447x over previous
//
#include <hip/hip_runtime.h>
#include <hip/hip_bf16.h>

// Problem constants (fixed by reference setup_inputs)
#define NN 100000
#define NE 1600000
#define ET 1700000   // NE + NN self loops
#define NEG_SLOPE 0.2f
#define EPSI 1e-16f

#define SCAN_NB 98
#define DEG_PAD (SCAN_NB * 1024)   // 100352

// Workspace layout (4-byte element offsets). Total ~12.7M elems = 50.8 MB.
#define OFF_WF     0         // [32]
#define OFF_AS1    32        // [NN*4]
#define OFF_AD1    400032    // [NN*4]
#define OFF_XW2    800032    // [NN*32]
#define OFF_AS2    4000032   // [NN]
#define OFF_AD2    4100032   // [NN]
#define OFF_OFFS   4200032   // [NN+1] int
#define OFF_CUR    4300034   // [NN] int
#define OFF_EDATA  4400034   // [ET] int2 (byte 17600136, 8B aligned)
#define OFF_DEG    7800036   // [DEG_PAD] int (byte 31200144, 16B aligned) -- zero zone
#define OFF_POOL   7900388   // [64]
#define OFF_BSUM   7900452   // [98] int
#define OFF_BPRE   7900550   // [100] int
#define OFF_OUT2   7900656   // [NN*32] (16B aligned)
#define OFF_MSG    11100656  // [NN*16] (16B aligned)
#define ZERO_START OFF_DEG
#define ZERO_N4    ((DEG_PAD + 64) / 4)

__device__ __forceinline__ float lrelu(float v) { return v > 0.f ? v : NEG_SLOPE * v; }

__global__ void kz(float4* __restrict__ p, int n4) {
    int st = gridDim.x * 256;
    for (int i = blockIdx.x * 256 + threadIdx.x; i < n4; i += st)
        p[i] = make_float4(0.f, 0.f, 0.f, 0.f);
}

// K0: fold W1 with att vectors: wf[k*4+h] = sum_f W1[k,h*32+f]*a[h,f]
__global__ void k0_wfold(const float* __restrict__ W1, const float* __restrict__ aS1,
                         const float* __restrict__ aD1, float* __restrict__ wf) {
    int t = threadIdx.x;
    if (t < 32) {
        int u = t & 15, k = u >> 2, h = u & 3;
        const float* av = (t < 16) ? aS1 : aD1;
        float s = 0.f;
        for (int f = 0; f < 32; f++) s += W1[k * 128 + h * 32 + f] * av[h * 32 + f];
        wf[t] = s;
    }
}

// K1: as1[n,h] = x[n,:]@wf[:,h]; ad1 likewise
__global__ void k1_att1(const float* __restrict__ x, const float* __restrict__ wf,
                        float* __restrict__ as1, float* __restrict__ ad1) {
    int n = blockIdx.x * 256 + threadIdx.x;
    if (n >= NN) return;
    float4 xv = *(const float4*)(x + n * 4);
#pragma unroll
    for (int h = 0; h < 4; h++) {
        as1[n * 4 + h] = xv.x * wf[h] + xv.y * wf[4 + h] + xv.z * wf[8 + h] + xv.w * wf[12 + h];
        ad1[n * 4 + h] = xv.x * wf[16 + h] + xv.y * wf[20 + h] + xv.z * wf[24 + h] + xv.w * wf[28 + h];
    }
}

// CSR: degree histogram
__global__ void kc1_deg(const int* __restrict__ ei, int* __restrict__ deg) {
    int e = blockIdx.x * 256 + threadIdx.x;
    if (e >= ET) return;
    int d_ = (e < NE) ? ei[NE + e] : (e - NE);
    atomicAdd(&deg[d_], 1);
}

// Two-level scan
__global__ void kc2a(const int* __restrict__ deg, int* __restrict__ bsum) {
    __shared__ int ws_[4];
    int b = blockIdx.x, t = threadIdx.x;
    int4 d = *(const int4*)(deg + b * 1024 + t * 4);
    int s = d.x + d.y + d.z + d.w;
#pragma unroll
    for (int m = 1; m < 64; m <<= 1) s += __shfl_xor(s, m);
    if ((t & 63) == 0) ws_[t >> 6] = s;
    __syncthreads();
    if (t == 0) bsum[b] = ws_[0] + ws_[1] + ws_[2] + ws_[3];
}

__global__ void kc2b(const int* __restrict__ bsum, int* __restrict__ bpre,
                     int* __restrict__ offs) {
    __shared__ int ts[128];
    int t = threadIdx.x;
    int v = (t < SCAN_NB) ? bsum[t] : 0;
    ts[t] = v;
    __syncthreads();
    for (int off = 1; off < 128; off <<= 1) {
        int u = (t >= off) ? ts[t - off] : 0;
        __syncthreads();
        ts[t] += u;
        __syncthreads();
    }
    if (t < SCAN_NB) bpre[t] = (t == 0) ? 0 : ts[t - 1];
    if (t == SCAN_NB - 1) offs[NN] = ts[t];
}

__global__ void kc2c(const int* __restrict__ deg, const int* __restrict__ bpre,
                     int* __restrict__ offs, int* __restrict__ cur) {
    __shared__ int ts[256];
    int b = blockIdx.x, t = threadIdx.x;
    int base = b * 1024 + t * 4;
    int4 d = *(const int4*)(deg + base);
    int s = d.x + d.y + d.z + d.w;
    ts[t] = s;
    __syncthreads();
    for (int off = 1; off < 256; off <<= 1) {
        int u = (t >= off) ? ts[t - off] : 0;
        __syncthreads();
        ts[t] += u;
        __syncthreads();
    }
    int r = bpre[b] + ((t == 0) ? 0 : ts[t - 1]);
    if (base < NN)     { offs[base] = r;     cur[base] = r; }     r += d.x;
    if (base + 1 < NN) { offs[base + 1] = r; cur[base + 1] = r; } r += d.y;
    if (base + 2 < NN) { offs[base + 2] = r; cur[base + 2] = r; } r += d.z;
    if (base + 3 < NN) { offs[base + 3] = r; cur[base + 3] = r; }
}

// CSR: fill (src, edge-id) per dst bucket
__global__ void kc3_fill(const int* __restrict__ ei, int* __restrict__ cursor,
                         int2* __restrict__ edata) {
    int e = blockIdx.x * 256 + threadIdx.x;
    if (e >= ET) return;
    int s_, d_;
    if (e < NE) { s_ = ei[e]; d_ = ei[NE + e]; } else { s_ = d_ = e - NE; }
    int pos = atomicAdd(&cursor[d_], 1);
    edata[pos] = make_int2(s_, e);
}

// K4a: conv1 edge gather, FACTORIZED: msg[n][h*4+k] = (sum_e exp_e * x[src_e][k]) / den_h
// 16 lanes per node: lane q = h + 4*p; head h, edge-split p=0..3.
__global__ __launch_bounds__(256) void k4a_gather(
    const int* __restrict__ offs, const int2* __restrict__ edata,
    const float* __restrict__ x, const float* __restrict__ as1,
    const float* __restrict__ ad1, float* __restrict__ msg) {
    int tid = threadIdx.x;
    int n = blockIdx.x * 16 + (tid >> 4);   // grid exact: 6250*16 = NN
    int q = tid & 15, h = q & 3, p = q >> 2;
    const int* ed32 = (const int*)edata;
    float ad = ad1[n * 4 + h];
    float z0 = 0.f, z1 = 0.f, z2 = 0.f, z3 = 0.f, den = 0.f;
    int beg = offs[n], end = offs[n + 1];
    for (int j = beg + p; j < end; j += 4) {
        int src = ed32[2 * j];
        float ex = __expf(lrelu(as1[src * 4 + h] + ad));
        float4 xv = *(const float4*)(x + src * 4);
        den += ex;
        z0 += ex * xv.x; z1 += ex * xv.y; z2 += ex * xv.z; z3 += ex * xv.w;
    }
#pragma unroll
    for (int m = 4; m <= 8; m <<= 1) {
        den += __shfl_xor(den, m);
        z0 += __shfl_xor(z0, m); z1 += __shfl_xor(z1, m);
        z2 += __shfl_xor(z2, m); z3 += __shfl_xor(z3, m);
    }
    if (p == 0) {
        float inv = 1.f / (den + EPSI);
        *(float4*)(msg + n * 16 + h * 4) = make_float4(z0 * inv, z1 * inv, z2 * inv, z3 * inv);
    }
}

// K4b: dense per-node: out1 = msg@W1 + b1 -> elu -> @W2 -> xw2, as2, ad2.
// One wave per node (4 nodes/block), lane owns cols f0=2*ln, f0+1.
__global__ __launch_bounds__(256) void k4b_dense(
    const float* __restrict__ msg, const float* __restrict__ W1,
    const float* __restrict__ b1, const float* __restrict__ W2,
    const float* __restrict__ aw_s2, const float* __restrict__ aw_d2,
    float* __restrict__ xw2, float* __restrict__ as2, float* __restrict__ ad2) {
    __shared__ float hs[4][128];
    int wv = threadIdx.x >> 6, ln = threadIdx.x & 63;
    int n = blockIdx.x * 4 + wv;            // grid exact: 25000*4 = NN
    int f0 = ln * 2;
    int h = f0 >> 5;
    float4 m = *(const float4*)(msg + n * 16 + h * 4);
    float h0 = m.x * W1[f0]     + m.y * W1[128 + f0]     + m.z * W1[256 + f0]     + m.w * W1[384 + f0]     + b1[f0];
    float h1 = m.x * W1[f0 + 1] + m.y * W1[128 + f0 + 1] + m.z * W1[256 + f0 + 1] + m.w * W1[384 + f0 + 1] + b1[f0 + 1];
    h0 = h0 > 0.f ? h0 : (__expf(h0) - 1.f);
    h1 = h1 > 0.f ? h1 : (__expf(h1) - 1.f);
    hs[wv][f0] = h0; hs[wv][f0 + 1] = h1;
    __syncthreads();
    int f = ln & 31, kb = (ln >> 5) * 64;
    float a = 0.f;
#pragma unroll
    for (int k = 0; k < 64; k++) a += hs[wv][kb + k] * W2[(kb + k) * 32 + f];
    a += __shfl_xor(a, 32);
    float ps = a * aw_s2[f], pd = a * aw_d2[f];
#pragma unroll
    for (int m2 = 1; m2 < 32; m2 <<= 1) { ps += __shfl_xor(ps, m2); pd += __shfl_xor(pd, m2); }
    if (ln < 32) xw2[n * 32 + f] = a;
    if (ln == 0) { as2[n] = ps; ad2[n] = pd; }
}

// K6: conv2 gather + attn write. 32 lanes per node, 8 nodes/block.
__global__ __launch_bounds__(256) void k6_conv2(
    const int* __restrict__ offs, const int2* __restrict__ edata,
    const float* __restrict__ xw2, const float* __restrict__ as2,
    const float* __restrict__ ad2, float* __restrict__ out2,
    float* __restrict__ attn) {
    int sub = threadIdx.x >> 5, f = threadIdx.x & 31;
    int n = blockIdx.x * 8 + sub;           // grid exact: 12500*8 = NN
    float ad = ad2[n];
    float den = 0.f, acc = 0.f;
    int beg = offs[n], end = offs[n + 1];
    for (int j = beg; j < end; j++) {
        int2 ed = edata[j];
        float ex = __expf(lrelu(as2[ed.x] + ad));
        den += ex;
        acc += ex * xw2[ed.x * 32 + f];
    }
    float inv = 1.f / (den + EPSI);
    out2[n * 32 + f] = acc * inv;
    for (int j = beg + f; j < end; j += 32) {
        int2 ed = edata[j];
        float ex = __expf(lrelu(as2[ed.x] + ad));
        attn[ed.y] = ex * inv;
    }
}

// K8: pooled sums
__global__ void k8_pool(const float* __restrict__ out2, const float* __restrict__ b2,
                        float* __restrict__ pool) {
    int tid = threadIdx.x;
    int f = tid & 31;
    float bb = b2[f];
    float acc = 0.f;
    int st = gridDim.x * 256;
    for (int i = blockIdx.x * 256 + tid; i < NN * 32; i += st) {
        float v = out2[i] + bb;
        acc += v > 0.f ? v : (__expf(v) - 1.f);
    }
    acc += __shfl_xor(acc, 32);
    if ((tid & 63) < 32) unsafeAtomicAdd(&pool[f], acc);
}

// K9: logits
__global__ void k9_logits(const float* __restrict__ pool, const float* __restrict__ lin_w,
                          const float* __restrict__ lin_b, float* __restrict__ out) {
    int j = threadIdx.x;
    if (j < 2) {
        float s = 0.f;
        for (int f = 0; f < 32; f++) s += (pool[f] * (1.0f / NN)) * lin_w[f * 2 + j];
        out[j] = s + lin_b[j];
    }
}

extern "C" void kernel_launch(void* const* d_in, const int* in_sizes, int n_in,
                              void* d_out, int out_size, void* d_ws, size_t ws_size,
                              hipStream_t stream) {
    const float* x    = (const float*)d_in[0];
    const int*   ei   = (const int*)d_in[1];
    const float* W1   = (const float*)d_in[2];
    const float* aS1  = (const float*)d_in[3];
    const float* aD1  = (const float*)d_in[4];
    const float* b1   = (const float*)d_in[5];
    const float* W2   = (const float*)d_in[6];
    const float* aS2  = (const float*)d_in[7];
    const float* aD2  = (const float*)d_in[8];
    const float* b2   = (const float*)d_in[9];
    const float* linw = (const float*)d_in[10];
    const float* linb = (const float*)d_in[11];

    float* ws   = (float*)d_ws;
    float* wf   = ws + OFF_WF;
    float* as1  = ws + OFF_AS1;
    float* ad1  = ws + OFF_AD1;
    float* xw2  = ws + OFF_XW2;
    float* as2  = ws + OFF_AS2;
    float* ad2  = ws + OFF_AD2;
    int*   offs = (int*)(ws + OFF_OFFS);
    int*   cur  = (int*)(ws + OFF_CUR);
    int2*  ed   = (int2*)(ws + OFF_EDATA);
    int*   deg  = (int*)(ws + OFF_DEG);
    float* pool = ws + OFF_POOL;
    int*   bsum = (int*)(ws + OFF_BSUM);
    int*   bpre = (int*)(ws + OFF_BPRE);
    float* out2 = ws + OFF_OUT2;
    float* msg  = ws + OFF_MSG;

    float* logits = (float*)d_out;
    float* attn   = (float*)d_out + 2;

    kz<<<98, 256, 0, stream>>>((float4*)(ws + ZERO_START), ZERO_N4);
    k0_wfold<<<1, 64, 0, stream>>>(W1, aS1, aD1, wf);
    k1_att1<<<(NN + 255) / 256, 256, 0, stream>>>(x, wf, as1, ad1);
    kc1_deg<<<(ET + 255) / 256, 256, 0, stream>>>(ei, deg);
    kc2a<<<SCAN_NB, 256, 0, stream>>>(deg, bsum);
    kc2b<<<1, 128, 0, stream>>>(bsum, bpre, offs);
    kc2c<<<SCAN_NB, 256, 0, stream>>>(deg, bpre, offs, cur);
    kc3_fill<<<(ET + 255) / 256, 256, 0, stream>>>(ei, cur, ed);
    k4a_gather<<<NN / 16, 256, 0, stream>>>(offs, ed, x, as1, ad1, msg);
    k4b_dense<<<NN / 4, 256, 0, stream>>>(msg, W1, b1, W2, aS2, aD2, xw2, as2, ad2);
    k6_conv2<<<NN / 8, 256, 0, stream>>>(offs, ed, xw2, as2, ad2, out2, attn);
    k8_pool<<<1024, 256, 0, stream>>>(out2, b2, pool);
    k9_logits<<<1, 64, 0, stream>>>(pool, linw, linb, logits);
}

// Round 7
// 374.888 us; speedup vs baseline: 10.7660x; 1.2349x over previous
//
#include <hip/hip_runtime.h>
#include <hip/hip_bf16.h>

// Problem constants (fixed by reference setup_inputs)
#define NN 100000
#define NE 1600000
#define ET 1700000   // NE + NN self loops
#define NEG_SLOPE 0.2f
#define EPSI 1e-16f

#define SCAN_NB 98
#define DEG_PAD (SCAN_NB * 1024)   // 100352

// Workspace layout (4-byte element offsets). Total ~12.7M elems = 50.8 MB.
#define OFF_WF     0         // [32]
#define OFF_AS1    32        // [NN*4]
#define OFF_AD1    400032    // [NN*4]
#define OFF_XW2    800032    // [NN*32]
#define OFF_AS2    4000032   // [NN]
#define OFF_AD2    4100032   // [NN]
#define OFF_DEN2I  4200032   // [NN]
#define OFF_OFFS   4300032   // [NN+1] int
#define OFF_RANK   4400034   // [ET] int
#define OFF_EDATA  6100034   // [ET] int (src node per CSR slot)
#define OFF_DEG    7800036   // [DEG_PAD] int (byte 31200144, 16B aligned) -- zero zone
#define OFF_POOL   7900388   // [64]
#define OFF_BSUM   7900452   // [112]
#define OFF_OUT2   7900656   // [NN*32] (16B aligned)
#define OFF_MSG    11100656  // [NN*16] (16B aligned)
#define ZERO_START OFF_DEG
#define ZERO_N4    ((DEG_PAD + 64) / 4)

__device__ __forceinline__ float lrelu(float v) { return v > 0.f ? v : NEG_SLOPE * v; }

__global__ void kz(float4* __restrict__ p, int n4) {
    int st = gridDim.x * 256;
    for (int i = blockIdx.x * 256 + threadIdx.x; i < n4; i += st)
        p[i] = make_float4(0.f, 0.f, 0.f, 0.f);
}

// K0: fold W1 with att vectors: wf[k*4+h] = sum_f W1[k,h*32+f]*a[h,f]
__global__ void k0_wfold(const float* __restrict__ W1, const float* __restrict__ aS1,
                         const float* __restrict__ aD1, float* __restrict__ wf) {
    int t = threadIdx.x;
    if (t < 32) {
        int u = t & 15, k = u >> 2, h = u & 3;
        const float* av = (t < 16) ? aS1 : aD1;
        float s = 0.f;
        for (int f = 0; f < 32; f++) s += W1[k * 128 + h * 32 + f] * av[h * 32 + f];
        wf[t] = s;
    }
}

// K1: as1[n,h] = x[n,:]@wf[:,h]; ad1 likewise
__global__ void k1_att1(const float* __restrict__ x, const float* __restrict__ wf,
                        float* __restrict__ as1, float* __restrict__ ad1) {
    int n = blockIdx.x * 256 + threadIdx.x;
    if (n >= NN) return;
    float4 xv = *(const float4*)(x + n * 4);
#pragma unroll
    for (int h = 0; h < 4; h++) {
        as1[n * 4 + h] = xv.x * wf[h] + xv.y * wf[4 + h] + xv.z * wf[8 + h] + xv.w * wf[12 + h];
        ad1[n * 4 + h] = xv.x * wf[16 + h] + xv.y * wf[20 + h] + xv.z * wf[24 + h] + xv.w * wf[28 + h];
    }
}

// CSR: degree histogram; atomic return value IS the edge's rank within its bucket
__global__ void kc1_deg(const int* __restrict__ ei, int* __restrict__ deg,
                        int* __restrict__ rank) {
    int e = blockIdx.x * 256 + threadIdx.x;
    if (e >= ET) return;
    int d_ = (e < NE) ? ei[NE + e] : (e - NE);
    rank[e] = atomicAdd(&deg[d_], 1);
}

// Scan phase A: per-block (1024 elems) sums
__global__ void kc2a(const int* __restrict__ deg, int* __restrict__ bsum) {
    __shared__ int ws_[4];
    int b = blockIdx.x, t = threadIdx.x;
    int4 d = *(const int4*)(deg + b * 1024 + t * 4);
    int s = d.x + d.y + d.z + d.w;
#pragma unroll
    for (int m = 1; m < 64; m <<= 1) s += __shfl_xor(s, m);
    if ((t & 63) == 0) ws_[t >> 6] = s;
    __syncthreads();
    if (t == 0) bsum[b] = ws_[0] + ws_[1] + ws_[2] + ws_[3];
}

// Scan phase C (B folded in): every block scans the 98 block sums, then intra-block
__global__ void kc2c(const int* __restrict__ deg, const int* __restrict__ bsum,
                     int* __restrict__ offs) {
    __shared__ int bs[128];
    __shared__ int ts[256];
    int b = blockIdx.x, t = threadIdx.x;
    if (t < 128) bs[t] = (t < SCAN_NB) ? bsum[t] : 0;
    __syncthreads();
    for (int off = 1; off < 128; off <<= 1) {
        int u = (t >= off && t < 128) ? bs[t - off] : 0;
        __syncthreads();
        if (t < 128) bs[t] += u;
        __syncthreads();
    }
    int bpre = (b == 0) ? 0 : bs[b - 1];
    int base = b * 1024 + t * 4;
    int4 d = *(const int4*)(deg + base);
    int s = d.x + d.y + d.z + d.w;
    ts[t] = s;
    __syncthreads();
    for (int off = 1; off < 256; off <<= 1) {
        int u = (t >= off) ? ts[t - off] : 0;
        __syncthreads();
        ts[t] += u;
        __syncthreads();
    }
    int r = bpre + ((t == 0) ? 0 : ts[t - 1]);
    if (base < NN)     offs[base] = r;     r += d.x;
    if (base + 1 < NN) offs[base + 1] = r; r += d.y;
    if (base + 2 < NN) offs[base + 2] = r; r += d.z;
    if (base + 3 < NN) offs[base + 3] = r;
    if (b == 0 && t == 0) offs[NN] = bs[SCAN_NB - 1];   // == ET
}

// CSR fill: NO atomic — position = offs[dst] + rank[e]
__global__ void kc3_fill(const int* __restrict__ ei, const int* __restrict__ offs,
                         const int* __restrict__ rank, int* __restrict__ edata) {
    int e = blockIdx.x * 256 + threadIdx.x;
    if (e >= ET) return;
    int s_, d_;
    if (e < NE) { s_ = ei[e]; d_ = ei[NE + e]; } else { s_ = d_ = e - NE; }
    edata[offs[d_] + rank[e]] = s_;
}

// K4a: conv1 edge gather, factorized. 16 lanes/node: lane q = h + 4*p.
__global__ __launch_bounds__(256) void k4a_gather(
    const int* __restrict__ offs, const int* __restrict__ edata,
    const float* __restrict__ x, const float* __restrict__ as1,
    const float* __restrict__ ad1, float* __restrict__ msg) {
    int tid = threadIdx.x;
    int n = blockIdx.x * 16 + (tid >> 4);   // grid exact: 6250*16 = NN
    int q = tid & 15, h = q & 3, p = q >> 2;
    float ad = ad1[n * 4 + h];
    float z0 = 0.f, z1 = 0.f, z2 = 0.f, z3 = 0.f, den = 0.f;
    int beg = offs[n], end = offs[n + 1];
    for (int j = beg + p; j < end; j += 4) {
        int src = edata[j];
        float ex = __expf(lrelu(as1[src * 4 + h] + ad));
        float4 xv = *(const float4*)(x + src * 4);
        den += ex;
        z0 += ex * xv.x; z1 += ex * xv.y; z2 += ex * xv.z; z3 += ex * xv.w;
    }
#pragma unroll
    for (int m = 4; m <= 8; m <<= 1) {
        den += __shfl_xor(den, m);
        z0 += __shfl_xor(z0, m); z1 += __shfl_xor(z1, m);
        z2 += __shfl_xor(z2, m); z3 += __shfl_xor(z3, m);
    }
    if (p == 0) {
        float inv = 1.f / (den + EPSI);
        *(float4*)(msg + n * 16 + h * 4) = make_float4(z0 * inv, z1 * inv, z2 * inv, z3 * inv);
    }
}

// K4b: dense per-node: out1 = msg@W1 + b1 -> elu -> @W2 -> xw2, as2, ad2.
__global__ __launch_bounds__(256) void k4b_dense(
    const float* __restrict__ msg, const float* __restrict__ W1,
    const float* __restrict__ b1, const float* __restrict__ W2,
    const float* __restrict__ aw_s2, const float* __restrict__ aw_d2,
    float* __restrict__ xw2, float* __restrict__ as2, float* __restrict__ ad2) {
    __shared__ float hs[4][128];
    int wv = threadIdx.x >> 6, ln = threadIdx.x & 63;
    int n = blockIdx.x * 4 + wv;            // grid exact: 25000*4 = NN
    int f0 = ln * 2;
    int h = f0 >> 5;
    float4 m = *(const float4*)(msg + n * 16 + h * 4);
    float h0 = m.x * W1[f0]     + m.y * W1[128 + f0]     + m.z * W1[256 + f0]     + m.w * W1[384 + f0]     + b1[f0];
    float h1 = m.x * W1[f0 + 1] + m.y * W1[128 + f0 + 1] + m.z * W1[256 + f0 + 1] + m.w * W1[384 + f0 + 1] + b1[f0 + 1];
    h0 = h0 > 0.f ? h0 : (__expf(h0) - 1.f);
    h1 = h1 > 0.f ? h1 : (__expf(h1) - 1.f);
    hs[wv][f0] = h0; hs[wv][f0 + 1] = h1;
    __syncthreads();
    int f = ln & 31, kb = (ln >> 5) * 64;
    float a = 0.f;
#pragma unroll
    for (int k = 0; k < 64; k++) a += hs[wv][kb + k] * W2[(kb + k) * 32 + f];
    a += __shfl_xor(a, 32);
    float ps = a * aw_s2[f], pd = a * aw_d2[f];
#pragma unroll
    for (int m2 = 1; m2 < 32; m2 <<= 1) { ps += __shfl_xor(ps, m2); pd += __shfl_xor(pd, m2); }
    if (ln < 32) xw2[n * 32 + f] = a;
    if (ln == 0) { as2[n] = ps; ad2[n] = pd; }
}

// K6: conv2 gather; also stores 1/den per node for the COO attn pass.
__global__ __launch_bounds__(256) void k6_conv2(
    const int* __restrict__ offs, const int* __restrict__ edata,
    const float* __restrict__ xw2, const float* __restrict__ as2,
    const float* __restrict__ ad2, float* __restrict__ out2,
    float* __restrict__ den2i) {
    int sub = threadIdx.x >> 5, f = threadIdx.x & 31;
    int n = blockIdx.x * 8 + sub;           // grid exact: 12500*8 = NN
    float ad = ad2[n];
    float den = 0.f, acc = 0.f;
    int beg = offs[n], end = offs[n + 1];
    for (int j = beg; j < end; j++) {
        int src = edata[j];
        float ex = __expf(lrelu(as2[src] + ad));
        den += ex;
        acc += ex * xw2[src * 32 + f];
    }
    float inv = 1.f / (den + EPSI);
    out2[n * 32 + f] = acc * inv;
    if (f == 0) den2i[n] = inv;
}

// K7: attn in COO order (coalesced writes)
__global__ void k7_attn(const int* __restrict__ ei, const float* __restrict__ as2,
                        const float* __restrict__ ad2, const float* __restrict__ den2i,
                        float* __restrict__ attn) {
    int e = blockIdx.x * 256 + threadIdx.x;
    if (e >= ET) return;
    int s_, d_;
    if (e < NE) { s_ = ei[e]; d_ = ei[NE + e]; } else { s_ = d_ = e - NE; }
    attn[e] = __expf(lrelu(as2[s_] + ad2[d_])) * den2i[d_];
}

// K8: pooled sums
__global__ void k8_pool(const float* __restrict__ out2, const float* __restrict__ b2,
                        float* __restrict__ pool) {
    int tid = threadIdx.x;
    int f = tid & 31;
    float bb = b2[f];
    float acc = 0.f;
    int st = gridDim.x * 256;
    for (int i = blockIdx.x * 256 + tid; i < NN * 32; i += st) {
        float v = out2[i] + bb;
        acc += v > 0.f ? v : (__expf(v) - 1.f);
    }
    acc += __shfl_xor(acc, 32);
    if ((tid & 63) < 32) unsafeAtomicAdd(&pool[f], acc);
}

// K9: logits
__global__ void k9_logits(const float* __restrict__ pool, const float* __restrict__ lin_w,
                          const float* __restrict__ lin_b, float* __restrict__ out) {
    int j = threadIdx.x;
    if (j < 2) {
        float s = 0.f;
        for (int f = 0; f < 32; f++) s += (pool[f] * (1.0f / NN)) * lin_w[f * 2 + j];
        out[j] = s + lin_b[j];
    }
}

extern "C" void kernel_launch(void* const* d_in, const int* in_sizes, int n_in,
                              void* d_out, int out_size, void* d_ws, size_t ws_size,
                              hipStream_t stream) {
    const float* x    = (const float*)d_in[0];
    const int*   ei   = (const int*)d_in[1];
    const float* W1   = (const float*)d_in[2];
    const float* aS1  = (const float*)d_in[3];
    const float* aD1  = (const float*)d_in[4];
    const float* b1   = (const float*)d_in[5];
    const float* W2   = (const float*)d_in[6];
    const float* aS2  = (const float*)d_in[7];
    const float* aD2  = (const float*)d_in[8];
    const float* b2   = (const float*)d_in[9];
    const float* linw = (const float*)d_in[10];
    const float* linb = (const float*)d_in[11];

    float* ws    = (float*)d_ws;
    float* wf    = ws + OFF_WF;
    float* as1   = ws + OFF_AS1;
    float* ad1   = ws + OFF_AD1;
    float* xw2   = ws + OFF_XW2;
    float* as2   = ws + OFF_AS2;
    float* ad2   = ws + OFF_AD2;
    float* den2i = ws + OFF_DEN2I;
    int*   offs  = (int*)(ws + OFF_OFFS);
    int*   rank  = (int*)(ws + OFF_RANK);
    int*   ed    = (int*)(ws + OFF_EDATA);
    int*   deg   = (int*)(ws + OFF_DEG);
    float* pool  = ws + OFF_POOL;
    int*   bsum  = (int*)(ws + OFF_BSUM);
    float* out2  = ws + OFF_OUT2;
    float* msg   = ws + OFF_MSG;

    float* logits = (float*)d_out;
    float* attn   = (float*)d_out + 2;

    kz<<<98, 256, 0, stream>>>((float4*)(ws + ZERO_START), ZERO_N4);
    k0_wfold<<<1, 64, 0, stream>>>(W1, aS1, aD1, wf);
    k1_att1<<<(NN + 255) / 256, 256, 0, stream>>>(x, wf, as1, ad1);
    kc1_deg<<<(ET + 255) / 256, 256, 0, stream>>>(ei, deg, rank);
    kc2a<<<SCAN_NB, 256, 0, stream>>>(deg, bsum);
    kc2c<<<SCAN_NB, 256, 0, stream>>>(deg, bsum, offs);
    kc3_fill<<<(ET + 255) / 256, 256, 0, stream>>>(ei, offs, rank, ed);
    k4a_gather<<<NN / 16, 256, 0, stream>>>(offs, ed, x, as1, ad1, msg);
    k4b_dense<<<NN / 4, 256, 0, stream>>>(msg, W1, b1, W2, aS2, aD2, xw2, as2, ad2);
    k6_conv2<<<NN / 8, 256, 0, stream>>>(offs, ed, xw2, as2, ad2, out2, den2i);
    k7_attn<<<(ET + 255) / 256, 256, 0, stream>>>(ei, as2, ad2, den2i, attn);
    k8_pool<<<1024, 256, 0, stream>>>(out2, b2, pool);
    k9_logits<<<1, 64, 0, stream>>>(pool, linw, linb, logits);
}

// Round 8
// 344.538 us; speedup vs baseline: 11.7144x; 1.0881x over previous
//
#include <hip/hip_runtime.h>
#include <hip/hip_bf16.h>
#include <hip/hip_fp16.h>

// Problem constants (fixed by reference setup_inputs)
#define NN 100000
#define NE 1600000
#define ET 1700000   // NE + NN self loops
#define NEG_SLOPE 0.2f
#define EPSI 1e-16f

#define SCAN_NB 98
#define DEG_PAD (SCAN_NB * 1024)   // 100352

// Workspace layout (4-byte element offsets). Total ~7.6M elems = 30.4 MB.
#define OFF_WF       0         // [32]
#define OFF_AS1      32        // [NN*4]
#define OFF_AD1      400032    // [NN*4]
#define OFF_AS2      800032    // [NN]
#define OFF_AD2      900032    // [NN]
#define OFF_DEN2I    1000032   // [NN]
#define OFF_XW2H     1100032   // [NN*32 halfs = NN*16 floats]
#define OFF_MSG      1900032   // [NN*16] (byte 7600128, 16B aligned)
#define OFF_OFFS     3500032   // [NN+1] int
#define OFF_RANK     3600034   // [ET] int
#define OFF_EDATA    5300034   // [ET] int
#define OFF_POOLPART 7000036   // [12500*32]
#define OFF_DEG      7400036   // [DEG_PAD] int (byte 29600144, 16B aligned) -- zero zone
#define OFF_POOL     7500388   // [64]
#define OFF_BSUM     7500452   // [112]
#define ZERO_START   OFF_DEG
#define ZERO_N4      ((DEG_PAD + 64) / 4)

__device__ __forceinline__ float lrelu(float v) { return v > 0.f ? v : NEG_SLOPE * v; }

__global__ void kz(float4* __restrict__ p, int n4) {
    int st = gridDim.x * 256;
    for (int i = blockIdx.x * 256 + threadIdx.x; i < n4; i += st)
        p[i] = make_float4(0.f, 0.f, 0.f, 0.f);
}

// K0: fold W1 with att vectors: wf[k*4+h] = sum_f W1[k,h*32+f]*a[h,f]
__global__ void k0_wfold(const float* __restrict__ W1, const float* __restrict__ aS1,
                         const float* __restrict__ aD1, float* __restrict__ wf) {
    int t = threadIdx.x;
    if (t < 32) {
        int u = t & 15, k = u >> 2, h = u & 3;
        const float* av = (t < 16) ? aS1 : aD1;
        float s = 0.f;
        for (int f = 0; f < 32; f++) s += W1[k * 128 + h * 32 + f] * av[h * 32 + f];
        wf[t] = s;
    }
}

// K1: as1[n,h] = x[n,:]@wf[:,h]; ad1 likewise
__global__ void k1_att1(const float* __restrict__ x, const float* __restrict__ wf,
                        float* __restrict__ as1, float* __restrict__ ad1) {
    int n = blockIdx.x * 256 + threadIdx.x;
    if (n >= NN) return;
    float4 xv = *(const float4*)(x + n * 4);
#pragma unroll
    for (int h = 0; h < 4; h++) {
        as1[n * 4 + h] = xv.x * wf[h] + xv.y * wf[4 + h] + xv.z * wf[8 + h] + xv.w * wf[12 + h];
        ad1[n * 4 + h] = xv.x * wf[16 + h] + xv.y * wf[20 + h] + xv.z * wf[24 + h] + xv.w * wf[28 + h];
    }
}

// CSR: degree histogram; atomic return value IS the edge's rank within its bucket
__global__ void kc1_deg(const int* __restrict__ ei, int* __restrict__ deg,
                        int* __restrict__ rank) {
    int e = blockIdx.x * 256 + threadIdx.x;
    if (e >= ET) return;
    int d_ = (e < NE) ? ei[NE + e] : (e - NE);
    rank[e] = atomicAdd(&deg[d_], 1);
}

// Scan phase A: per-block (1024 elems) sums
__global__ void kc2a(const int* __restrict__ deg, int* __restrict__ bsum) {
    __shared__ int ws_[4];
    int b = blockIdx.x, t = threadIdx.x;
    int4 d = *(const int4*)(deg + b * 1024 + t * 4);
    int s = d.x + d.y + d.z + d.w;
#pragma unroll
    for (int m = 1; m < 64; m <<= 1) s += __shfl_xor(s, m);
    if ((t & 63) == 0) ws_[t >> 6] = s;
    __syncthreads();
    if (t == 0) bsum[b] = ws_[0] + ws_[1] + ws_[2] + ws_[3];
}

// Scan phase C: every block scans the 98 block sums, then intra-block
__global__ void kc2c(const int* __restrict__ deg, const int* __restrict__ bsum,
                     int* __restrict__ offs) {
    __shared__ int bs[128];
    __shared__ int ts[256];
    int b = blockIdx.x, t = threadIdx.x;
    if (t < 128) bs[t] = (t < SCAN_NB) ? bsum[t] : 0;
    __syncthreads();
    for (int off = 1; off < 128; off <<= 1) {
        int u = (t >= off && t < 128) ? bs[t - off] : 0;
        __syncthreads();
        if (t < 128) bs[t] += u;
        __syncthreads();
    }
    int bpre = (b == 0) ? 0 : bs[b - 1];
    int base = b * 1024 + t * 4;
    int4 d = *(const int4*)(deg + base);
    int s = d.x + d.y + d.z + d.w;
    ts[t] = s;
    __syncthreads();
    for (int off = 1; off < 256; off <<= 1) {
        int u = (t >= off) ? ts[t - off] : 0;
        __syncthreads();
        ts[t] += u;
        __syncthreads();
    }
    int r = bpre + ((t == 0) ? 0 : ts[t - 1]);
    if (base < NN)     offs[base] = r;     r += d.x;
    if (base + 1 < NN) offs[base + 1] = r; r += d.y;
    if (base + 2 < NN) offs[base + 2] = r; r += d.z;
    if (base + 3 < NN) offs[base + 3] = r;
    if (b == 0 && t == 0) offs[NN] = bs[SCAN_NB - 1];   // == ET
}

// CSR fill: NO atomic — position = offs[dst] + rank[e]
__global__ void kc3_fill(const int* __restrict__ ei, const int* __restrict__ offs,
                         const int* __restrict__ rank, int* __restrict__ edata) {
    int e = blockIdx.x * 256 + threadIdx.x;
    if (e >= ET) return;
    int s_, d_;
    if (e < NE) { s_ = ei[e]; d_ = ei[NE + e]; } else { s_ = d_ = e - NE; }
    edata[offs[d_] + rank[e]] = s_;
}

// K4a: conv1 edge gather, factorized. 16 lanes/node: lane q = h + 4*p.
__global__ __launch_bounds__(256) void k4a_gather(
    const int* __restrict__ offs, const int* __restrict__ edata,
    const float* __restrict__ x, const float* __restrict__ as1,
    const float* __restrict__ ad1, float* __restrict__ msg) {
    int tid = threadIdx.x;
    int n = blockIdx.x * 16 + (tid >> 4);   // grid exact: 6250*16 = NN
    int q = tid & 15, h = q & 3, p = q >> 2;
    float ad = ad1[n * 4 + h];
    float z0 = 0.f, z1 = 0.f, z2 = 0.f, z3 = 0.f, den = 0.f;
    int beg = offs[n], end = offs[n + 1];
    for (int j = beg + p; j < end; j += 4) {
        int src = edata[j];
        float ex = __expf(lrelu(as1[src * 4 + h] + ad));
        float4 xv = *(const float4*)(x + src * 4);
        den += ex;
        z0 += ex * xv.x; z1 += ex * xv.y; z2 += ex * xv.z; z3 += ex * xv.w;
    }
#pragma unroll
    for (int m = 4; m <= 8; m <<= 1) {
        den += __shfl_xor(den, m);
        z0 += __shfl_xor(z0, m); z1 += __shfl_xor(z1, m);
        z2 += __shfl_xor(z2, m); z3 += __shfl_xor(z3, m);
    }
    if (p == 0) {
        float inv = 1.f / (den + EPSI);
        *(float4*)(msg + n * 16 + h * 4) = make_float4(z0 * inv, z1 * inv, z2 * inv, z3 * inv);
    }
}

// K4b: dense per-node: out1 = msg@W1 + b1 -> elu -> @W2 -> xw2h (fp16), as2, ad2 (fp32).
__global__ __launch_bounds__(256) void k4b_dense(
    const float* __restrict__ msg, const float* __restrict__ W1,
    const float* __restrict__ b1, const float* __restrict__ W2,
    const float* __restrict__ aw_s2, const float* __restrict__ aw_d2,
    __half* __restrict__ xw2h, float* __restrict__ as2, float* __restrict__ ad2) {
    __shared__ float hs[4][128];
    int wv = threadIdx.x >> 6, ln = threadIdx.x & 63;
    int n = blockIdx.x * 4 + wv;            // grid exact: 25000*4 = NN
    int f0 = ln * 2;
    int h = f0 >> 5;
    float4 m = *(const float4*)(msg + n * 16 + h * 4);
    float h0 = m.x * W1[f0]     + m.y * W1[128 + f0]     + m.z * W1[256 + f0]     + m.w * W1[384 + f0]     + b1[f0];
    float h1 = m.x * W1[f0 + 1] + m.y * W1[128 + f0 + 1] + m.z * W1[256 + f0 + 1] + m.w * W1[384 + f0 + 1] + b1[f0 + 1];
    h0 = h0 > 0.f ? h0 : (__expf(h0) - 1.f);
    h1 = h1 > 0.f ? h1 : (__expf(h1) - 1.f);
    hs[wv][f0] = h0; hs[wv][f0 + 1] = h1;
    __syncthreads();
    int f = ln & 31, kb = (ln >> 5) * 64;
    float a = 0.f;
#pragma unroll
    for (int k = 0; k < 64; k++) a += hs[wv][kb + k] * W2[(kb + k) * 32 + f];
    a += __shfl_xor(a, 32);
    float ps = a * aw_s2[f], pd = a * aw_d2[f];
#pragma unroll
    for (int m2 = 1; m2 < 32; m2 <<= 1) { ps += __shfl_xor(ps, m2); pd += __shfl_xor(pd, m2); }
    if (ln < 32) xw2h[n * 32 + f] = __float2half_rn(a);
    if (ln == 0) { as2[n] = ps; ad2[n] = pd; }
}

// K6: conv2 gather (fp16 payload) + fused elu-bias-pool partial. No out2 buffer.
__global__ __launch_bounds__(256) void k6_conv2(
    const int* __restrict__ offs, const int* __restrict__ edata,
    const __half* __restrict__ xw2h, const float* __restrict__ as2,
    const float* __restrict__ ad2, const float* __restrict__ b2,
    float* __restrict__ den2i, float* __restrict__ pool_part) {
    __shared__ float psum[4][32];
    int sub = threadIdx.x >> 5, f = threadIdx.x & 31;
    int n = blockIdx.x * 8 + sub;           // grid exact: 12500*8 = NN
    float ad = ad2[n];
    float den = 0.f, acc = 0.f;
    int beg = offs[n], end = offs[n + 1];
    for (int j = beg; j < end; j++) {
        int src = edata[j];
        float ex = __expf(lrelu(as2[src] + ad));
        den += ex;
        acc += ex * __half2float(xw2h[src * 32 + f]);
    }
    float inv = 1.f / (den + EPSI);
    if (f == 0) den2i[n] = inv;
    float v = acc * inv + b2[f];
    v = v > 0.f ? v : (__expf(v) - 1.f);
    v += __shfl_xor(v, 32);                 // combine the wave's two subs
    int wv = threadIdx.x >> 6;
    if ((threadIdx.x & 63) < 32) psum[wv][f] = v;
    __syncthreads();
    if (threadIdx.x < 32)
        pool_part[blockIdx.x * 32 + f] = psum[0][f] + psum[1][f] + psum[2][f] + psum[3][f];
}

// K7: attn in COO order (coalesced writes)
__global__ void k7_attn(const int* __restrict__ ei, const float* __restrict__ as2,
                        const float* __restrict__ ad2, const float* __restrict__ den2i,
                        float* __restrict__ attn) {
    int e = blockIdx.x * 256 + threadIdx.x;
    if (e >= ET) return;
    int s_, d_;
    if (e < NE) { s_ = ei[e]; d_ = ei[NE + e]; } else { s_ = d_ = e - NE; }
    attn[e] = __expf(lrelu(as2[s_] + ad2[d_])) * den2i[d_];
}

// K8: reduce pool partials (elu+bias already applied in k6)
__global__ void k8_pool(const float* __restrict__ pool_part, float* __restrict__ pool) {
    int tid = threadIdx.x;
    int f = tid & 31;
    float acc = 0.f;
    int st = gridDim.x * 256;
    for (int i = blockIdx.x * 256 + tid; i < 12500 * 32; i += st) acc += pool_part[i];
    acc += __shfl_xor(acc, 32);
    if ((tid & 63) < 32) unsafeAtomicAdd(&pool[f], acc);
}

// K9: logits
__global__ void k9_logits(const float* __restrict__ pool, const float* __restrict__ lin_w,
                          const float* __restrict__ lin_b, float* __restrict__ out) {
    int j = threadIdx.x;
    if (j < 2) {
        float s = 0.f;
        for (int f = 0; f < 32; f++) s += (pool[f] * (1.0f / NN)) * lin_w[f * 2 + j];
        out[j] = s + lin_b[j];
    }
}

extern "C" void kernel_launch(void* const* d_in, const int* in_sizes, int n_in,
                              void* d_out, int out_size, void* d_ws, size_t ws_size,
                              hipStream_t stream) {
    const float* x    = (const float*)d_in[0];
    const int*   ei   = (const int*)d_in[1];
    const float* W1   = (const float*)d_in[2];
    const float* aS1  = (const float*)d_in[3];
    const float* aD1  = (const float*)d_in[4];
    const float* b1   = (const float*)d_in[5];
    const float* W2   = (const float*)d_in[6];
    const float* aS2  = (const float*)d_in[7];
    const float* aD2  = (const float*)d_in[8];
    const float* b2   = (const float*)d_in[9];
    const float* linw = (const float*)d_in[10];
    const float* linb = (const float*)d_in[11];

    float*  ws    = (float*)d_ws;
    float*  wf    = ws + OFF_WF;
    float*  as1   = ws + OFF_AS1;
    float*  ad1   = ws + OFF_AD1;
    float*  as2   = ws + OFF_AS2;
    float*  ad2   = ws + OFF_AD2;
    float*  den2i = ws + OFF_DEN2I;
    __half* xw2h  = (__half*)(ws + OFF_XW2H);
    float*  msg   = ws + OFF_MSG;
    int*    offs  = (int*)(ws + OFF_OFFS);
    int*    rank  = (int*)(ws + OFF_RANK);
    int*    ed    = (int*)(ws + OFF_EDATA);
    float*  ppart = ws + OFF_POOLPART;
    int*    deg   = (int*)(ws + OFF_DEG);
    float*  pool  = ws + OFF_POOL;
    int*    bsum  = (int*)(ws + OFF_BSUM);

    float* logits = (float*)d_out;
    float* attn   = (float*)d_out + 2;

    kz<<<98, 256, 0, stream>>>((float4*)(ws + ZERO_START), ZERO_N4);
    k0_wfold<<<1, 64, 0, stream>>>(W1, aS1, aD1, wf);
    k1_att1<<<(NN + 255) / 256, 256, 0, stream>>>(x, wf, as1, ad1);
    kc1_deg<<<(ET + 255) / 256, 256, 0, stream>>>(ei, deg, rank);
    kc2a<<<SCAN_NB, 256, 0, stream>>>(deg, bsum);
    kc2c<<<SCAN_NB, 256, 0, stream>>>(deg, bsum, offs);
    kc3_fill<<<(ET + 255) / 256, 256, 0, stream>>>(ei, offs, rank, ed);
    k4a_gather<<<NN / 16, 256, 0, stream>>>(offs, ed, x, as1, ad1, msg);
    k4b_dense<<<NN / 4, 256, 0, stream>>>(msg, W1, b1, W2, aS2, aD2, xw2h, as2, ad2);
    k6_conv2<<<NN / 8, 256, 0, stream>>>(offs, ed, xw2h, as2, ad2, b2, den2i, ppart);
    k7_attn<<<(ET + 255) / 256, 256, 0, stream>>>(ei, as2, ad2, den2i, attn);
    k8_pool<<<256, 256, 0, stream>>>(ppart, pool);
    k9_logits<<<1, 64, 0, stream>>>(pool, linw, linb, logits);
}

// Round 9
// 310.059 us; speedup vs baseline: 13.0171x; 1.1112x over previous
//
#include <hip/hip_runtime.h>
#include <hip/hip_bf16.h>
#include <hip/hip_fp16.h>

// Problem constants (fixed by reference setup_inputs)
#define NN 100000
#define NE 1600000
#define ET 1700000   // NE + NN self loops
#define NEG_SLOPE 0.2f
#define EPSI 1e-16f

#define SCAN_NB 98
#define DEG_PAD (SCAN_NB * 1024)   // 100352

// Workspace layout (4-byte element offsets). Total ~7.6M elems = 30.4 MB.
#define OFF_WF       0         // [32]
#define OFF_AS1      32        // [NN*4]
#define OFF_AD1      400032    // [NN*4]
#define OFF_AS2      800032    // [NN]
#define OFF_AD2      900032    // [NN]
#define OFF_DEN2I    1000032   // [NN]
#define OFF_XW2H     1100032   // [NN*32 halfs = NN*16 floats]
#define OFF_MSG      1900032   // [NN*16] (byte 7600128, 16B aligned)
#define OFF_OFFS     3500032   // [NN+1] int
#define OFF_RANK     3600034   // [ET] int
#define OFF_EDATA    5300034   // [ET] int
#define OFF_POOLPART 7000036   // [12500*32]
#define OFF_DEG      7400036   // [DEG_PAD] int (byte 29600144, 16B aligned) -- zero zone
#define OFF_POOL     7500388   // [64]
#define OFF_BSUM     7500452   // [112]
#define ZERO_START   OFF_DEG
#define ZERO_N4      ((DEG_PAD + 64) / 4)

__device__ __forceinline__ float lrelu(float v) { return v > 0.f ? v : NEG_SLOPE * v; }

__global__ void kz(float4* __restrict__ p, int n4) {
    int st = gridDim.x * 256;
    for (int i = blockIdx.x * 256 + threadIdx.x; i < n4; i += st)
        p[i] = make_float4(0.f, 0.f, 0.f, 0.f);
}

// K0: fold W1 with att vectors: wf[k*4+h] = sum_f W1[k,h*32+f]*a[h,f]
__global__ void k0_wfold(const float* __restrict__ W1, const float* __restrict__ aS1,
                         const float* __restrict__ aD1, float* __restrict__ wf) {
    int t = threadIdx.x;
    if (t < 32) {
        int u = t & 15, k = u >> 2, h = u & 3;
        const float* av = (t < 16) ? aS1 : aD1;
        float s = 0.f;
        for (int f = 0; f < 32; f++) s += W1[k * 128 + h * 32 + f] * av[h * 32 + f];
        wf[t] = s;
    }
}

// K1: as1[n,h] = x[n,:]@wf[:,h]; ad1 likewise
__global__ void k1_att1(const float* __restrict__ x, const float* __restrict__ wf,
                        float* __restrict__ as1, float* __restrict__ ad1) {
    int n = blockIdx.x * 256 + threadIdx.x;
    if (n >= NN) return;
    float4 xv = *(const float4*)(x + n * 4);
#pragma unroll
    for (int h = 0; h < 4; h++) {
        as1[n * 4 + h] = xv.x * wf[h] + xv.y * wf[4 + h] + xv.z * wf[8 + h] + xv.w * wf[12 + h];
        ad1[n * 4 + h] = xv.x * wf[16 + h] + xv.y * wf[20 + h] + xv.z * wf[24 + h] + xv.w * wf[28 + h];
    }
}

// CSR: degree histogram; atomic return value IS the edge's rank within its bucket
__global__ void kc1_deg(const int* __restrict__ ei, int* __restrict__ deg,
                        int* __restrict__ rank) {
    int e = blockIdx.x * 256 + threadIdx.x;
    if (e >= ET) return;
    int d_ = (e < NE) ? ei[NE + e] : (e - NE);
    rank[e] = atomicAdd(&deg[d_], 1);
}

// Scan phase A: per-block (1024 elems) sums
__global__ void kc2a(const int* __restrict__ deg, int* __restrict__ bsum) {
    __shared__ int ws_[4];
    int b = blockIdx.x, t = threadIdx.x;
    int4 d = *(const int4*)(deg + b * 1024 + t * 4);
    int s = d.x + d.y + d.z + d.w;
#pragma unroll
    for (int m = 1; m < 64; m <<= 1) s += __shfl_xor(s, m);
    if ((t & 63) == 0) ws_[t >> 6] = s;
    __syncthreads();
    if (t == 0) bsum[b] = ws_[0] + ws_[1] + ws_[2] + ws_[3];
}

// Scan phase C: every block scans the 98 block sums, then intra-block
__global__ void kc2c(const int* __restrict__ deg, const int* __restrict__ bsum,
                     int* __restrict__ offs) {
    __shared__ int bs[128];
    __shared__ int ts[256];
    int b = blockIdx.x, t = threadIdx.x;
    if (t < 128) bs[t] = (t < SCAN_NB) ? bsum[t] : 0;
    __syncthreads();
    for (int off = 1; off < 128; off <<= 1) {
        int u = (t >= off && t < 128) ? bs[t - off] : 0;
        __syncthreads();
        if (t < 128) bs[t] += u;
        __syncthreads();
    }
    int bpre = (b == 0) ? 0 : bs[b - 1];
    int base = b * 1024 + t * 4;
    int4 d = *(const int4*)(deg + base);
    int s = d.x + d.y + d.z + d.w;
    ts[t] = s;
    __syncthreads();
    for (int off = 1; off < 256; off <<= 1) {
        int u = (t >= off) ? ts[t - off] : 0;
        __syncthreads();
        ts[t] += u;
        __syncthreads();
    }
    int r = bpre + ((t == 0) ? 0 : ts[t - 1]);
    if (base < NN)     offs[base] = r;     r += d.x;
    if (base + 1 < NN) offs[base + 1] = r; r += d.y;
    if (base + 2 < NN) offs[base + 2] = r; r += d.z;
    if (base + 3 < NN) offs[base + 3] = r;
    if (b == 0 && t == 0) offs[NN] = bs[SCAN_NB - 1];   // == ET
}

// CSR fill: NO atomic — position = offs[dst] + rank[e]
__global__ void kc3_fill(const int* __restrict__ ei, const int* __restrict__ offs,
                         const int* __restrict__ rank, int* __restrict__ edata) {
    int e = blockIdx.x * 256 + threadIdx.x;
    if (e >= ET) return;
    int s_, d_;
    if (e < NE) { s_ = ei[e]; d_ = ei[NE + e]; } else { s_ = d_ = e - NE; }
    edata[offs[d_] + rank[e]] = s_;
}

// K4a: conv1 edge gather, factorized. 16 lanes/node: lane q = h + 4*p.
__global__ __launch_bounds__(256) void k4a_gather(
    const int* __restrict__ offs, const int* __restrict__ edata,
    const float* __restrict__ x, const float* __restrict__ as1,
    const float* __restrict__ ad1, float* __restrict__ msg) {
    int tid = threadIdx.x;
    int n = blockIdx.x * 16 + (tid >> 4);   // grid exact: 6250*16 = NN
    int q = tid & 15, h = q & 3, p = q >> 2;
    float ad = ad1[n * 4 + h];
    float z0 = 0.f, z1 = 0.f, z2 = 0.f, z3 = 0.f, den = 0.f;
    int beg = offs[n], end = offs[n + 1];
    for (int j = beg + p; j < end; j += 4) {
        int src = edata[j];
        float ex = __expf(lrelu(as1[src * 4 + h] + ad));
        float4 xv = *(const float4*)(x + src * 4);
        den += ex;
        z0 += ex * xv.x; z1 += ex * xv.y; z2 += ex * xv.z; z3 += ex * xv.w;
    }
#pragma unroll
    for (int m = 4; m <= 8; m <<= 1) {
        den += __shfl_xor(den, m);
        z0 += __shfl_xor(z0, m); z1 += __shfl_xor(z1, m);
        z2 += __shfl_xor(z2, m); z3 += __shfl_xor(z3, m);
    }
    if (p == 0) {
        float inv = 1.f / (den + EPSI);
        *(float4*)(msg + n * 16 + h * 4) = make_float4(z0 * inv, z1 * inv, z2 * inv, z3 * inv);
    }
}

// K4b: dense per-node: out1 = msg@W1 + b1 -> elu -> @W2 -> xw2h (fp16), as2, ad2 (fp32).
__global__ __launch_bounds__(256) void k4b_dense(
    const float* __restrict__ msg, const float* __restrict__ W1,
    const float* __restrict__ b1, const float* __restrict__ W2,
    const float* __restrict__ aw_s2, const float* __restrict__ aw_d2,
    __half* __restrict__ xw2h, float* __restrict__ as2, float* __restrict__ ad2) {
    __shared__ float hs[4][128];
    int wv = threadIdx.x >> 6, ln = threadIdx.x & 63;
    int n = blockIdx.x * 4 + wv;            // grid exact: 25000*4 = NN
    int f0 = ln * 2;
    int h = f0 >> 5;
    float4 m = *(const float4*)(msg + n * 16 + h * 4);
    float h0 = m.x * W1[f0]     + m.y * W1[128 + f0]     + m.z * W1[256 + f0]     + m.w * W1[384 + f0]     + b1[f0];
    float h1 = m.x * W1[f0 + 1] + m.y * W1[128 + f0 + 1] + m.z * W1[256 + f0 + 1] + m.w * W1[384 + f0 + 1] + b1[f0 + 1];
    h0 = h0 > 0.f ? h0 : (__expf(h0) - 1.f);
    h1 = h1 > 0.f ? h1 : (__expf(h1) - 1.f);
    hs[wv][f0] = h0; hs[wv][f0 + 1] = h1;
    __syncthreads();
    int f = ln & 31, kb = (ln >> 5) * 64;
    float a = 0.f;
#pragma unroll
    for (int k = 0; k < 64; k++) a += hs[wv][kb + k] * W2[(kb + k) * 32 + f];
    a += __shfl_xor(a, 32);
    float ps = a * aw_s2[f], pd = a * aw_d2[f];
#pragma unroll
    for (int m2 = 1; m2 < 32; m2 <<= 1) { ps += __shfl_xor(ps, m2); pd += __shfl_xor(pd, m2); }
    if (ln < 32) xw2h[n * 32 + f] = __float2half_rn(a);
    if (ln == 0) { as2[n] = ps; ad2[n] = pd; }
}

// K6: conv2 gather, edge-parallel restructure:
// phase1: 32 lanes load 32 consecutive edges (coalesced) + compute 32 exps in parallel;
// phase2: shfl-broadcast (src,ex) per edge, pipelined xw2h line gathers.
// Fused elu-bias-pool partial; no out2 buffer.
__global__ __launch_bounds__(256) void k6_conv2(
    const int* __restrict__ offs, const int* __restrict__ edata,
    const __half* __restrict__ xw2h, const float* __restrict__ as2,
    const float* __restrict__ ad2, const float* __restrict__ b2,
    float* __restrict__ den2i, float* __restrict__ pool_part) {
    __shared__ float psum[4][32];
    int sub = threadIdx.x >> 5, f = threadIdx.x & 31;
    int n = blockIdx.x * 8 + sub;           // grid exact: 12500*8 = NN
    float ad = ad2[n];
    float den = 0.f, acc = 0.f;
    int beg = offs[n], end = offs[n + 1];
    for (int base = beg; base < end; base += 32) {
        int j = base + f;
        int src = 0;
        float ex = 0.f;
        if (j < end) {
            src = edata[j];                          // coalesced
            ex = __expf(lrelu(as2[src] + ad));       // 32 exps in parallel
        }
        den += ex;
        int cnt = min(32, end - base);
        for (int k = 0; k < cnt; k++) {
            int   sk = __shfl(src, k, 32);
            float ek = __shfl(ex, k, 32);
            acc += ek * __half2float(xw2h[sk * 32 + f]);
        }
    }
#pragma unroll
    for (int m = 1; m < 32; m <<= 1) den += __shfl_xor(den, m, 32);
    float inv = 1.f / (den + EPSI);
    if (f == 0) den2i[n] = inv;
    float v = acc * inv + b2[f];
    v = v > 0.f ? v : (__expf(v) - 1.f);
    v += __shfl_xor(v, 32);                 // combine the wave's two subs
    int wv = threadIdx.x >> 6;
    if ((threadIdx.x & 63) < 32) psum[wv][f] = v;
    __syncthreads();
    if (threadIdx.x < 32)
        pool_part[blockIdx.x * 32 + f] = psum[0][f] + psum[1][f] + psum[2][f] + psum[3][f];
}

// K7: attn in COO order (coalesced writes)
__global__ void k7_attn(const int* __restrict__ ei, const float* __restrict__ as2,
                        const float* __restrict__ ad2, const float* __restrict__ den2i,
                        float* __restrict__ attn) {
    int e = blockIdx.x * 256 + threadIdx.x;
    if (e >= ET) return;
    int s_, d_;
    if (e < NE) { s_ = ei[e]; d_ = ei[NE + e]; } else { s_ = d_ = e - NE; }
    attn[e] = __expf(lrelu(as2[s_] + ad2[d_])) * den2i[d_];
}

// K8: reduce pool partials (elu+bias already applied in k6)
__global__ void k8_pool(const float* __restrict__ pool_part, float* __restrict__ pool) {
    int tid = threadIdx.x;
    int f = tid & 31;
    float acc = 0.f;
    int st = gridDim.x * 256;
    for (int i = blockIdx.x * 256 + tid; i < 12500 * 32; i += st) acc += pool_part[i];
    acc += __shfl_xor(acc, 32);
    if ((tid & 63) < 32) unsafeAtomicAdd(&pool[f], acc);
}

// K9: logits
__global__ void k9_logits(const float* __restrict__ pool, const float* __restrict__ lin_w,
                          const float* __restrict__ lin_b, float* __restrict__ out) {
    int j = threadIdx.x;
    if (j < 2) {
        float s = 0.f;
        for (int f = 0; f < 32; f++) s += (pool[f] * (1.0f / NN)) * lin_w[f * 2 + j];
        out[j] = s + lin_b[j];
    }
}

extern "C" void kernel_launch(void* const* d_in, const int* in_sizes, int n_in,
                              void* d_out, int out_size, void* d_ws, size_t ws_size,
                              hipStream_t stream) {
    const float* x    = (const float*)d_in[0];
    const int*   ei   = (const int*)d_in[1];
    const float* W1   = (const float*)d_in[2];
    const float* aS1  = (const float*)d_in[3];
    const float* aD1  = (const float*)d_in[4];
    const float* b1   = (const float*)d_in[5];
    const float* W2   = (const float*)d_in[6];
    const float* aS2  = (const float*)d_in[7];
    const float* aD2  = (const float*)d_in[8];
    const float* b2   = (const float*)d_in[9];
    const float* linw = (const float*)d_in[10];
    const float* linb = (const float*)d_in[11];

    float*  ws    = (float*)d_ws;
    float*  wf    = ws + OFF_WF;
    float*  as1   = ws + OFF_AS1;
    float*  ad1   = ws + OFF_AD1;
    float*  as2   = ws + OFF_AS2;
    float*  ad2   = ws + OFF_AD2;
    float*  den2i = ws + OFF_DEN2I;
    __half* xw2h  = (__half*)(ws + OFF_XW2H);
    float*  msg   = ws + OFF_MSG;
    int*    offs  = (int*)(ws + OFF_OFFS);
    int*    rank  = (int*)(ws + OFF_RANK);
    int*    ed    = (int*)(ws + OFF_EDATA);
    float*  ppart = ws + OFF_POOLPART;
    int*    deg   = (int*)(ws + OFF_DEG);
    float*  pool  = ws + OFF_POOL;
    int*    bsum  = (int*)(ws + OFF_BSUM);

    float* logits = (float*)d_out;
    float* attn   = (float*)d_out + 2;

    kz<<<98, 256, 0, stream>>>((float4*)(ws + ZERO_START), ZERO_N4);
    k0_wfold<<<1, 64, 0, stream>>>(W1, aS1, aD1, wf);
    k1_att1<<<(NN + 255) / 256, 256, 0, stream>>>(x, wf, as1, ad1);
    kc1_deg<<<(ET + 255) / 256, 256, 0, stream>>>(ei, deg, rank);
    kc2a<<<SCAN_NB, 256, 0, stream>>>(deg, bsum);
    kc2c<<<SCAN_NB, 256, 0, stream>>>(deg, bsum, offs);
    kc3_fill<<<(ET + 255) / 256, 256, 0, stream>>>(ei, offs, rank, ed);
    k4a_gather<<<NN / 16, 256, 0, stream>>>(offs, ed, x, as1, ad1, msg);
    k4b_dense<<<NN / 4, 256, 0, stream>>>(msg, W1, b1, W2, aS2, aD2, xw2h, as2, ad2);
    k6_conv2<<<NN / 8, 256, 0, stream>>>(offs, ed, xw2h, as2, ad2, b2, den2i, ppart);
    k7_attn<<<(ET + 255) / 256, 256, 0, stream>>>(ei, as2, ad2, den2i, attn);
    k8_pool<<<256, 256, 0, stream>>>(ppart, pool);
    k9_logits<<<1, 64, 0, stream>>>(pool, linw, linb, logits);
}

// Round 10
// 303.985 us; speedup vs baseline: 13.2772x; 1.0200x over previous
//
#include <hip/hip_runtime.h>
#include <hip/hip_bf16.h>
#include <hip/hip_fp16.h>

// Problem constants (fixed by reference setup_inputs)
#define NN 100000
#define NE 1600000
#define ET 1700000   // NE + NN self loops
#define NEG_SLOPE 0.2f
#define EPSI 1e-16f

#define SCAN_NB 98
#define DEG_PAD (SCAN_NB * 1024)   // 100352

// Workspace layout (4-byte element offsets).
#define OFF_WF       0         // [32]
#define OFF_AS1      32        // [NN*4]
#define OFF_AD1      400032    // [NN*4]
#define OFF_AS2      800032    // [NN]
#define OFF_AD2      900032    // [NN]
#define OFF_DEN2I    1000032   // [NN]
#define OFF_XW2H     1100032   // [NN*32 halfs = NN*16 floats]
#define OFF_OFFS     3500032   // [NN+1] int
#define OFF_RANK     3600034   // [ET] int
#define OFF_EDATA    5300034   // [ET] int
#define OFF_POOLPART 7000036   // [12500*32]
#define OFF_DEG      7400036   // [DEG_PAD] int (byte 29600144, 16B aligned) -- zero zone
#define OFF_POOL     7500388   // [64]
#define OFF_BSUM     7500452   // [112]
#define ZERO_START   OFF_DEG
#define ZERO_N4      ((DEG_PAD + 64) / 4)

__device__ __forceinline__ float lrelu(float v) { return v > 0.f ? v : NEG_SLOPE * v; }

__global__ void kz(float4* __restrict__ p, int n4) {
    int st = gridDim.x * 256;
    for (int i = blockIdx.x * 256 + threadIdx.x; i < n4; i += st)
        p[i] = make_float4(0.f, 0.f, 0.f, 0.f);
}

// K0: fold W1 with att vectors: wf[k*4+h] = sum_f W1[k,h*32+f]*a[h,f]
__global__ void k0_wfold(const float* __restrict__ W1, const float* __restrict__ aS1,
                         const float* __restrict__ aD1, float* __restrict__ wf) {
    int t = threadIdx.x;
    if (t < 32) {
        int u = t & 15, k = u >> 2, h = u & 3;
        const float* av = (t < 16) ? aS1 : aD1;
        float s = 0.f;
        for (int f = 0; f < 32; f++) s += W1[k * 128 + h * 32 + f] * av[h * 32 + f];
        wf[t] = s;
    }
}

// K1: as1[n,h] = x[n,:]@wf[:,h]; ad1 likewise
__global__ void k1_att1(const float* __restrict__ x, const float* __restrict__ wf,
                        float* __restrict__ as1, float* __restrict__ ad1) {
    int n = blockIdx.x * 256 + threadIdx.x;
    if (n >= NN) return;
    float4 xv = *(const float4*)(x + n * 4);
#pragma unroll
    for (int h = 0; h < 4; h++) {
        as1[n * 4 + h] = xv.x * wf[h] + xv.y * wf[4 + h] + xv.z * wf[8 + h] + xv.w * wf[12 + h];
        ad1[n * 4 + h] = xv.x * wf[16 + h] + xv.y * wf[20 + h] + xv.z * wf[24 + h] + xv.w * wf[28 + h];
    }
}

// CSR: degree histogram; atomic return value IS the edge's rank within its bucket
__global__ void kc1_deg(const int* __restrict__ ei, int* __restrict__ deg,
                        int* __restrict__ rank) {
    int e = blockIdx.x * 256 + threadIdx.x;
    if (e >= ET) return;
    int d_ = (e < NE) ? ei[NE + e] : (e - NE);
    rank[e] = atomicAdd(&deg[d_], 1);
}

// Scan phase A: per-block (1024 elems) sums
__global__ void kc2a(const int* __restrict__ deg, int* __restrict__ bsum) {
    __shared__ int ws_[4];
    int b = blockIdx.x, t = threadIdx.x;
    int4 d = *(const int4*)(deg + b * 1024 + t * 4);
    int s = d.x + d.y + d.z + d.w;
#pragma unroll
    for (int m = 1; m < 64; m <<= 1) s += __shfl_xor(s, m);
    if ((t & 63) == 0) ws_[t >> 6] = s;
    __syncthreads();
    if (t == 0) bsum[b] = ws_[0] + ws_[1] + ws_[2] + ws_[3];
}

// Scan phase C: every block scans the 98 block sums, then intra-block
__global__ void kc2c(const int* __restrict__ deg, const int* __restrict__ bsum,
                     int* __restrict__ offs) {
    __shared__ int bs[128];
    __shared__ int ts[256];
    int b = blockIdx.x, t = threadIdx.x;
    if (t < 128) bs[t] = (t < SCAN_NB) ? bsum[t] : 0;
    __syncthreads();
    for (int off = 1; off < 128; off <<= 1) {
        int u = (t >= off && t < 128) ? bs[t - off] : 0;
        __syncthreads();
        if (t < 128) bs[t] += u;
        __syncthreads();
    }
    int bpre = (b == 0) ? 0 : bs[b - 1];
    int base = b * 1024 + t * 4;
    int4 d = *(const int4*)(deg + base);
    int s = d.x + d.y + d.z + d.w;
    ts[t] = s;
    __syncthreads();
    for (int off = 1; off < 256; off <<= 1) {
        int u = (t >= off) ? ts[t - off] : 0;
        __syncthreads();
        ts[t] += u;
        __syncthreads();
    }
    int r = bpre + ((t == 0) ? 0 : ts[t - 1]);
    if (base < NN)     offs[base] = r;     r += d.x;
    if (base + 1 < NN) offs[base + 1] = r; r += d.y;
    if (base + 2 < NN) offs[base + 2] = r; r += d.z;
    if (base + 3 < NN) offs[base + 3] = r;
    if (b == 0 && t == 0) offs[NN] = bs[SCAN_NB - 1];   // == ET
}

// CSR fill: NO atomic — position = offs[dst] + rank[e]
__global__ void kc3_fill(const int* __restrict__ ei, const int* __restrict__ offs,
                         const int* __restrict__ rank, int* __restrict__ edata) {
    int e = blockIdx.x * 256 + threadIdx.x;
    if (e >= ET) return;
    int s_, d_;
    if (e < NE) { s_ = ei[e]; d_ = ei[NE + e]; } else { s_ = d_ = e - NE; }
    edata[offs[d_] + rank[e]] = s_;
}

// K4AB: fused conv1 gather + dense (msg never hits memory).
// One wave per node. Gather: h=ln&3, p=ln>>2 (16-way edge split), xor-reduce,
// shfl-broadcast normalized msg. Dense: lane owns cols f0=2ln, f0+1; h@W2 via
// float4 LDS reads; outputs xw2h (fp16), as2, ad2 (fp32).
__global__ __launch_bounds__(256) void k4ab(
    const int* __restrict__ offs, const int* __restrict__ edata,
    const float* __restrict__ x, const float* __restrict__ as1,
    const float* __restrict__ ad1, const float* __restrict__ W1,
    const float* __restrict__ b1, const float* __restrict__ W2,
    const float* __restrict__ aw_s2, const float* __restrict__ aw_d2,
    __half* __restrict__ xw2h, float* __restrict__ as2, float* __restrict__ ad2) {
    __shared__ float hs[4][128];
    int wv = threadIdx.x >> 6, ln = threadIdx.x & 63;
    int n = blockIdx.x * 4 + wv;            // grid exact: 25000*4 = NN
    // ---- gather phase ----
    int hq = ln & 3, p = ln >> 2;
    float ad = ad1[n * 4 + hq];
    float z0 = 0.f, z1 = 0.f, z2 = 0.f, z3 = 0.f, den = 0.f;
    int beg = offs[n], end = offs[n + 1];
    for (int j = beg + p; j < end; j += 16) {
        int src = edata[j];
        float ex = __expf(lrelu(as1[src * 4 + hq] + ad));
        float4 xv = *(const float4*)(x + src * 4);
        den += ex;
        z0 += ex * xv.x; z1 += ex * xv.y; z2 += ex * xv.z; z3 += ex * xv.w;
    }
#pragma unroll
    for (int m = 4; m <= 32; m <<= 1) {
        den += __shfl_xor(den, m);
        z0 += __shfl_xor(z0, m); z1 += __shfl_xor(z1, m);
        z2 += __shfl_xor(z2, m); z3 += __shfl_xor(z3, m);
    }
    float inv = 1.f / (den + EPSI);
    float v0 = z0 * inv, v1 = z1 * inv, v2 = z2 * inv, v3 = z3 * inv;
    // ---- dense phase: msg via shfl (head h lives in lane h) ----
    int f0 = ln * 2, h = ln >> 4;
    float mx = __shfl(v0, h), my = __shfl(v1, h), mz = __shfl(v2, h), mw = __shfl(v3, h);
    float h0 = mx * W1[f0]     + my * W1[128 + f0]     + mz * W1[256 + f0]     + mw * W1[384 + f0]     + b1[f0];
    float h1 = mx * W1[f0 + 1] + my * W1[128 + f0 + 1] + mz * W1[256 + f0 + 1] + mw * W1[384 + f0 + 1] + b1[f0 + 1];
    h0 = h0 > 0.f ? h0 : (__expf(h0) - 1.f);
    h1 = h1 > 0.f ? h1 : (__expf(h1) - 1.f);
    hs[wv][f0] = h0; hs[wv][f0 + 1] = h1;
    __syncthreads();
    int f = ln & 31, kb = (ln >> 5) * 64;
    const float* hrow = &hs[wv][kb];
    float a = 0.f;
#pragma unroll
    for (int k = 0; k < 64; k += 4) {
        float4 hv = *(const float4*)(hrow + k);
        a += hv.x * W2[(kb + k) * 32 + f];
        a += hv.y * W2[(kb + k + 1) * 32 + f];
        a += hv.z * W2[(kb + k + 2) * 32 + f];
        a += hv.w * W2[(kb + k + 3) * 32 + f];
    }
    a += __shfl_xor(a, 32);
    float ps = a * aw_s2[f], pd = a * aw_d2[f];
#pragma unroll
    for (int m2 = 1; m2 < 32; m2 <<= 1) { ps += __shfl_xor(ps, m2); pd += __shfl_xor(pd, m2); }
    if (ln < 32) xw2h[n * 32 + f] = __float2half_rn(a);
    if (ln == 0) { as2[n] = ps; ad2[n] = pd; }
}

// K6: conv2 gather, edge-parallel (coalesced edata + parallel exps, shfl-broadcast
// pipelined xw2h line gathers); fused elu-bias-pool partial.
__global__ __launch_bounds__(256) void k6_conv2(
    const int* __restrict__ offs, const int* __restrict__ edata,
    const __half* __restrict__ xw2h, const float* __restrict__ as2,
    const float* __restrict__ ad2, const float* __restrict__ b2,
    float* __restrict__ den2i, float* __restrict__ pool_part) {
    __shared__ float psum[4][32];
    int sub = threadIdx.x >> 5, f = threadIdx.x & 31;
    int n = blockIdx.x * 8 + sub;           // grid exact: 12500*8 = NN
    float ad = ad2[n];
    float den = 0.f, acc = 0.f;
    int beg = offs[n], end = offs[n + 1];
    for (int base = beg; base < end; base += 32) {
        int j = base + f;
        int src = 0;
        float ex = 0.f;
        if (j < end) {
            src = edata[j];                          // coalesced
            ex = __expf(lrelu(as2[src] + ad));       // 32 exps in parallel
        }
        den += ex;
        int cnt = min(32, end - base);
        for (int k = 0; k < cnt; k++) {
            int   sk = __shfl(src, k, 32);
            float ek = __shfl(ex, k, 32);
            acc += ek * __half2float(xw2h[sk * 32 + f]);
        }
    }
#pragma unroll
    for (int m = 1; m < 32; m <<= 1) den += __shfl_xor(den, m, 32);
    float inv = 1.f / (den + EPSI);
    if (f == 0) den2i[n] = inv;
    float v = acc * inv + b2[f];
    v = v > 0.f ? v : (__expf(v) - 1.f);
    v += __shfl_xor(v, 32);                 // combine the wave's two subs
    int wv = threadIdx.x >> 6;
    if ((threadIdx.x & 63) < 32) psum[wv][f] = v;
    __syncthreads();
    if (threadIdx.x < 32)
        pool_part[blockIdx.x * 32 + f] = psum[0][f] + psum[1][f] + psum[2][f] + psum[3][f];
}

// K7: attn in COO order (coalesced writes)
__global__ void k7_attn(const int* __restrict__ ei, const float* __restrict__ as2,
                        const float* __restrict__ ad2, const float* __restrict__ den2i,
                        float* __restrict__ attn) {
    int e = blockIdx.x * 256 + threadIdx.x;
    if (e >= ET) return;
    int s_, d_;
    if (e < NE) { s_ = ei[e]; d_ = ei[NE + e]; } else { s_ = d_ = e - NE; }
    attn[e] = __expf(lrelu(as2[s_] + ad2[d_])) * den2i[d_];
}

// K8: reduce pool partials (elu+bias already applied in k6)
__global__ void k8_pool(const float* __restrict__ pool_part, float* __restrict__ pool) {
    int tid = threadIdx.x;
    int f = tid & 31;
    float acc = 0.f;
    int st = gridDim.x * 256;
    for (int i = blockIdx.x * 256 + tid; i < 12500 * 32; i += st) acc += pool_part[i];
    acc += __shfl_xor(acc, 32);
    if ((tid & 63) < 32) unsafeAtomicAdd(&pool[f], acc);
}

// K9: logits
__global__ void k9_logits(const float* __restrict__ pool, const float* __restrict__ lin_w,
                          const float* __restrict__ lin_b, float* __restrict__ out) {
    int j = threadIdx.x;
    if (j < 2) {
        float s = 0.f;
        for (int f = 0; f < 32; f++) s += (pool[f] * (1.0f / NN)) * lin_w[f * 2 + j];
        out[j] = s + lin_b[j];
    }
}

extern "C" void kernel_launch(void* const* d_in, const int* in_sizes, int n_in,
                              void* d_out, int out_size, void* d_ws, size_t ws_size,
                              hipStream_t stream) {
    const float* x    = (const float*)d_in[0];
    const int*   ei   = (const int*)d_in[1];
    const float* W1   = (const float*)d_in[2];
    const float* aS1  = (const float*)d_in[3];
    const float* aD1  = (const float*)d_in[4];
    const float* b1   = (const float*)d_in[5];
    const float* W2   = (const float*)d_in[6];
    const float* aS2  = (const float*)d_in[7];
    const float* aD2  = (const float*)d_in[8];
    const float* b2   = (const float*)d_in[9];
    const float* linw = (const float*)d_in[10];
    const float* linb = (const float*)d_in[11];

    float*  ws    = (float*)d_ws;
    float*  wf    = ws + OFF_WF;
    float*  as1   = ws + OFF_AS1;
    float*  ad1   = ws + OFF_AD1;
    float*  as2   = ws + OFF_AS2;
    float*  ad2   = ws + OFF_AD2;
    float*  den2i = ws + OFF_DEN2I;
    __half* xw2h  = (__half*)(ws + OFF_XW2H);
    int*    offs  = (int*)(ws + OFF_OFFS);
    int*    rank  = (int*)(ws + OFF_RANK);
    int*    ed    = (int*)(ws + OFF_EDATA);
    float*  ppart = ws + OFF_POOLPART;
    int*    deg   = (int*)(ws + OFF_DEG);
    float*  pool  = ws + OFF_POOL;
    int*    bsum  = (int*)(ws + OFF_BSUM);

    float* logits = (float*)d_out;
    float* attn   = (float*)d_out + 2;

    kz<<<98, 256, 0, stream>>>((float4*)(ws + ZERO_START), ZERO_N4);
    k0_wfold<<<1, 64, 0, stream>>>(W1, aS1, aD1, wf);
    k1_att1<<<(NN + 255) / 256, 256, 0, stream>>>(x, wf, as1, ad1);
    kc1_deg<<<(ET + 255) / 256, 256, 0, stream>>>(ei, deg, rank);
    kc2a<<<SCAN_NB, 256, 0, stream>>>(deg, bsum);
    kc2c<<<SCAN_NB, 256, 0, stream>>>(deg, bsum, offs);
    kc3_fill<<<(ET + 255) / 256, 256, 0, stream>>>(ei, offs, rank, ed);
    k4ab<<<NN / 4, 256, 0, stream>>>(offs, ed, x, as1, ad1, W1, b1, W2,
                                     aS2, aD2, xw2h, as2, ad2);
    k6_conv2<<<NN / 8, 256, 0, stream>>>(offs, ed, xw2h, as2, ad2, b2, den2i, ppart);
    k7_attn<<<(ET + 255) / 256, 256, 0, stream>>>(ei, as2, ad2, den2i, attn);
    k8_pool<<<256, 256, 0, stream>>>(ppart, pool);
    k9_logits<<<1, 64, 0, stream>>>(pool, linw, linb, logits);
}